// Round 4
// baseline (282.334 us; speedup 1.0000x reference)
//
#include <hip/hip_runtime.h>

// LstmSequential round 4: barrier-minimal MFMA recurrence.
//  prep_e1   : ONE kernel. blocks 0..255 compute E1h[v][u][g] fp16 = b1 + emb[v]@W1
//              (coalesced fp16 stores); blocks 256..319 pack U1 / [W2;U2] into MFMA
//              B-fragment layout (fp16).
//  lstm_mfma : both LSTM layers + head fused, 256 blocks x 4 waves, 16 rows/block.
//              Ping-pong LDS A-buffer -> ONE __syncthreads per timestep (hazard
//              analysis: epi1 writes buf[1-p] h1 pre-barrier, epi2 writes buf[1-p] h2
//              post-barrier; every RAW/WAR pair crosses >=1 barrier).
//              E1 gather is fp16 (5MB, ~L2-resident) issued right after the barrier ->
//              ~600cyc overlap window before the next vmcnt(0) drain.
//              Activations: (5,4)-Pade tanh + clamp (1 trans op instead of exp+div).
// Fallback to round-1 monolithic kernel if ws too small.

#define VOCAB 10000
#define EMB   100
#define SEQ   80
#define BATCH 4096

typedef _Float16 f16;
typedef _Float16 f16x8 __attribute__((ext_vector_type(8)));
typedef _Float16 half2_t __attribute__((ext_vector_type(2)));
typedef float    f32x4 __attribute__((ext_vector_type(4)));
typedef unsigned int uint;

__device__ __forceinline__ uint pack2(float lo, float hi) {
    return __builtin_bit_cast(uint, __builtin_amdgcn_cvt_pkrtz(lo, hi));
}
__device__ __forceinline__ uint rl_u(uint v, int l) { return (uint)__builtin_amdgcn_readlane((int)v, l); }
__device__ __forceinline__ float dot2(uint a, uint b, float c) {
    return __builtin_amdgcn_fdot2(__builtin_bit_cast(half2_t, a), __builtin_bit_cast(half2_t, b), c, false);
}
__device__ __forceinline__ f32x4 mfma16(uint4 a, uint4 b, f32x4 c) {
    return __builtin_amdgcn_mfma_f32_16x16x32_f16(
        __builtin_bit_cast(f16x8, a), __builtin_bit_cast(f16x8, b), c, 0, 0, 0);
}

// (5,4)-Pade tanh, clamped to [-1,1]. |err| < 7e-4 for all x (max near |x|~3-4),
// < 1e-5 for |x|<=1.5 (operating range here: z ~ N(0, ~0.1)).
__device__ __forceinline__ float tanh_p(float x) {
    float x2  = x * x;
    float num = x * __builtin_fmaf(x2, 105.0f + x2, 945.0f);
    float den = __builtin_fmaf(x2, __builtin_fmaf(15.0f, x2, 420.0f), 945.0f);
    float r   = __fdividef(num, den);
    return __builtin_fmaxf(-1.0f, __builtin_fminf(1.0f, r));
}
__device__ __forceinline__ float sigm_p(float x) {
    return __builtin_fmaf(0.5f, tanh_p(0.5f * x), 0.5f);
}
__device__ __forceinline__ float sigm_exact(float x) {
    return __fdividef(1.0f, 1.0f + __expf(-x));
}

// ---------------- workspace layout (bytes) ----------------
#define WS_E1H_OFF 0                 // VOCAB*256 f16  = 5,120,000
#define WS_B1F_OFF 5120000           // 2048 uint4     = 32,768
#define WS_B2F_OFF 5152768           // 4096 uint4     = 65,536
#define WS_NEEDED  5218304

// ---------------- prep_e1: E1 table + B-fragment packing, one kernel ----------------
// B-frag mapping (16x16x32 f16): lane holds B[k = kt*32 + (lane>>4)*8 + j][n = lane&15],
// dword dw holds j=2dw (lo), j=2dw+1 (hi).
__global__ __launch_bounds__(256) void prep_e1(
    const float* __restrict__ emb,
    const float* __restrict__ W1, const float* __restrict__ U1,
    const float* __restrict__ b1,
    const float* __restrict__ W2, const float* __restrict__ U2,
    f16* __restrict__ E1h, uint* __restrict__ B1f, uint* __restrict__ B2f) {
    if (blockIdx.x < 256) {
        // ---- role A: E1h[v*256 + u*4 + g] = b1[g*64+u] + emb[v] @ W1[:, g*64+u] ----
        const int c    = threadIdx.x;
        const int lane = c & 63;
        const int col  = (c & 3) * 64 + (c >> 2);     // gate-minor storage -> coalesced store
        uint w[50];
#pragma unroll
        for (int kp = 0; kp < 50; ++kp)
            w[kp] = pack2(W1[(2 * kp) * 256 + col], W1[(2 * kp + 1) * 256 + col]);
        const float bias = b1[col];
        for (int v = blockIdx.x; v < VOCAB; v += 256) {
            uint ep = 0;
            if (lane < 50) ep = pack2(emb[v * EMB + 2 * lane], emb[v * EMB + 2 * lane + 1]);
            float acc = bias;
#pragma unroll
            for (int kp = 0; kp < 50; ++kp) acc = dot2(w[kp], rl_u(ep, kp), acc);
            E1h[v * 256 + c] = (f16)acc;
        }
    } else {
        // ---- role B: fragment packing ----
        int idx = (blockIdx.x - 256) * 256 + threadIdx.x;   // 0..16383
        if (idx < 8192) {                                   // B1f (U1, 64x256)
            int dw = idx & 3, lane = (idx >> 2) & 63, kt = (idx >> 8) & 1,
                g = (idx >> 9) & 3, w = idx >> 11;
            int k   = kt * 32 + (lane >> 4) * 8 + dw * 2;
            int col = g * 64 + w * 16 + (lane & 15);
            B1f[idx] = pack2(U1[k * 256 + col], U1[(k + 1) * 256 + col]);
        }
        if (idx < 16384) {                                  // B2f ([W2;U2], 128x256)
            int dw = idx & 3, lane = (idx >> 2) & 63, kt = (idx >> 8) & 3,
                g = (idx >> 10) & 3, w = idx >> 12;
            int k   = kt * 32 + (lane >> 4) * 8 + dw * 2;
            int col = g * 64 + w * 16 + (lane & 15);
            float lo = (k < 64) ? W2[k * 256 + col] : U2[(k - 64) * 256 + col];
            float hi = (k < 63) ? W2[(k + 1) * 256 + col] : U2[(k + 1 - 64) * 256 + col];
            B2f[idx] = pack2(lo, hi);
        }
    }
}

// ---------------- fused 2-layer LSTM + head, 1 barrier per step ----------------
// A-buffer (per ping-pong buf b): fp16 A-matrix [16 m x 128 k] in fragment layout,
//   f16 index of (m,k) = ((k>>3)*16 + m)*8 + (k&7); lane's kt-frag = uint4 [kt*64+lane].
//   k 0..63 = h1, k 64..127 = h2.
// Step t (parity p): MFMA1 reads buf[p] h1 | epi1 writes buf[1-p] h1 | BARRIER |
//   MFMA2 reads buf[1-p] h1 + buf[p] h2 | epi2 writes buf[1-p] h2 | p ^= 1.
__global__ __launch_bounds__(256, 1) void lstm_mfma(
    const int* __restrict__ tokens, const uint2* __restrict__ E1h2,
    const uint4* __restrict__ B1f, const uint4* __restrict__ B2f,
    const float* __restrict__ b2, const float* __restrict__ Wd,
    const float* __restrict__ bd, float* __restrict__ out) {
    __shared__ uint4 AbufU[512];                  // 2 bufs x 256 uint4 = 8 KB
    __shared__ float red[64];
    f16* Abuf = (f16*)AbufU;

    const int tid  = threadIdx.x;
    const int w    = tid >> 6;
    const int lane = tid & 63;
    const int q    = lane >> 4;
    const int li   = lane & 15;
    const int u    = w * 16 + li;                 // this lane's unit
    const int row0 = blockIdx.x * 16;

    const uint4 z4 = {0u, 0u, 0u, 0u};
    AbufU[tid] = z4; AbufU[tid + 256] = z4;       // h1[-1] = h2[-1] = 0

    // persistent B fragments
    uint4 b1f[4][2], b2f[4][4];
#pragma unroll
    for (int g = 0; g < 4; ++g) {
#pragma unroll
        for (int kt = 0; kt < 2; ++kt) b1f[g][kt] = B1f[((w * 4 + g) * 2 + kt) * 64 + lane];
#pragma unroll
        for (int kt = 0; kt < 4; ++kt) b2f[g][kt] = B2f[((w * 4 + g) * 4 + kt) * 64 + lane];
    }
    float b2v[4];
#pragma unroll
    for (int g = 0; g < 4; ++g) b2v[g] = b2[g * 64 + u];
    const float wdv = Wd[u];
    const float bdv = bd[0];

    // token windows (rows q*4+r) + E1 prefetch for t=0
    int4  tokc[4], tokn[4];
    uint2 e1c[4], e1n[4];
#pragma unroll
    for (int r = 0; r < 4; ++r) {
        tokc[r] = *(const int4*)(tokens + (size_t)(row0 + q * 4 + r) * SEQ);
        e1c[r]  = E1h2[(size_t)tokc[r].x * 64 + u];
    }

    float c1[4] = {0.f, 0.f, 0.f, 0.f}, c2[4] = {0.f, 0.f, 0.f, 0.f};
    float h2v[4] = {0.f, 0.f, 0.f, 0.f};

    int p = 0;
    __syncthreads();                              // zeros + nothing else pending

#pragma unroll 1
    for (int t4 = 0; t4 < SEQ / 4; ++t4) {
        if (t4 < SEQ / 4 - 1) {
#pragma unroll
            for (int r = 0; r < 4; ++r)
                tokn[r] = *(const int4*)(tokens + (size_t)(row0 + q * 4 + r) * SEQ + (t4 + 1) * 4);
        }
#pragma unroll
        for (int s = 0; s < 4; ++s) {
            // ---- layer 1 MFMA: z1 = h1_{t-1} @ U1 ----
            uint4 a0 = AbufU[p * 256 + lane];
            uint4 a1 = AbufU[p * 256 + 64 + lane];
            f32x4 acc[4] = {{0,0,0,0},{0,0,0,0},{0,0,0,0},{0,0,0,0}};
#pragma unroll
            for (int g = 0; g < 4; ++g) acc[g] = mfma16(a0, b1f[g][0], acc[g]);
#pragma unroll
            for (int g = 0; g < 4; ++g) acc[g] = mfma16(a1, b1f[g][1], acc[g]);

            // ---- epilogue 1 (lane-local), writes h1_t -> buf[1-p] ----
#pragma unroll
            for (int r = 0; r < 4; ++r) {
                half2_t e01 = __builtin_bit_cast(half2_t, e1c[r].x);
                half2_t e23 = __builtin_bit_cast(half2_t, e1c[r].y);
                float ig = sigm_p(acc[0][r] + (float)e01.x);
                float fg = sigm_p(acc[1][r] + (float)e01.y);
                float gv = tanh_p(acc[2][r] + (float)e23.x);
                float og = sigm_p(acc[3][r] + (float)e23.y);
                c1[r] = fg * c1[r] + ig * gv;
                float h1 = og * tanh_p(c1[r]);
                Abuf[(1 - p) * 2048 + ((u >> 3) * 16 + q * 4 + r) * 8 + (u & 7)] = (f16)h1;
            }

            __syncthreads();                      // the ONE barrier of this step

            // prefetch E1 for t+1 (drains at next step's barrier: ~full-step window)
            if (t4 * 4 + s + 1 < SEQ) {
#pragma unroll
                for (int r = 0; r < 4; ++r) {
                    int tk = (s == 0) ? tokc[r].y : (s == 1) ? tokc[r].z
                           : (s == 2) ? tokc[r].w : tokn[r].x;
                    e1n[r] = E1h2[(size_t)tk * 64 + u];
                }
            }

            // ---- layer 2 MFMA: z2 = [h1_t | h2_{t-1}] @ [W2;U2] ----
            uint4 a[4];
            a[0] = AbufU[(1 - p) * 256 + lane];
            a[1] = AbufU[(1 - p) * 256 + 64 + lane];
            a[2] = AbufU[p * 256 + 128 + lane];
            a[3] = AbufU[p * 256 + 192 + lane];
            f32x4 acc2[4] = {{0,0,0,0},{0,0,0,0},{0,0,0,0},{0,0,0,0}};
#pragma unroll
            for (int kt = 0; kt < 4; ++kt)
#pragma unroll
                for (int g = 0; g < 4; ++g) acc2[g] = mfma16(a[kt], b2f[g][kt], acc2[g]);

            // ---- epilogue 2 (lane-local), writes h2_t -> buf[1-p] ----
#pragma unroll
            for (int r = 0; r < 4; ++r) {
                float ig = sigm_p(acc2[0][r] + b2v[0]);
                float fg = sigm_p(acc2[1][r] + b2v[1]);
                float gv = tanh_p(acc2[2][r] + b2v[2]);
                float og = sigm_p(acc2[3][r] + b2v[3]);
                c2[r] = fg * c2[r] + ig * gv;
                float h2 = og * tanh_p(c2[r]);
                h2v[r] = h2;
                Abuf[(1 - p) * 2048 + 1024 + ((u >> 3) * 16 + q * 4 + r) * 8 + (u & 7)] = (f16)h2;
            }
#pragma unroll
            for (int r = 0; r < 4; ++r) e1c[r] = e1n[r];
            p ^= 1;
        }
        if (t4 < SEQ / 4 - 1) {
#pragma unroll
            for (int r = 0; r < 4; ++r) tokc[r] = tokn[r];
        }
    }

    // ---- head: out[row] = sigmoid(sum_u h2[row][u]*Wd[u] + bd), exact exp ----
#pragma unroll
    for (int r = 0; r < 4; ++r) {
        float pv = h2v[r] * wdv;
        pv += __shfl_xor(pv, 1, 64);
        pv += __shfl_xor(pv, 2, 64);
        pv += __shfl_xor(pv, 4, 64);
        pv += __shfl_xor(pv, 8, 64);
        if (li == 0) red[w * 16 + q * 4 + r] = pv;
    }
    __syncthreads();
    if (tid < 16) {
        float sum = red[tid] + red[16 + tid] + red[32 + tid] + red[48 + tid] + bdv;
        out[row0 + tid] = sigm_exact(sum);
    }
}

// ---------------- fallback (no workspace): round-1 monolithic ----------------
__device__ __forceinline__ float lane_bcast(float v, int j) {
    return __builtin_bit_cast(float, __builtin_amdgcn_readlane(__builtin_bit_cast(int, v), j));
}
__device__ __forceinline__ float sigm_f(float x)  { return 1.0f / (1.0f + __expf(-x)); }
__device__ __forceinline__ float tanh_f(float x)  { return 2.0f / (1.0f + __expf(-2.0f * x)) - 1.0f; }

__global__ __launch_bounds__(512) void lstm_fused_fallback(
    const int* __restrict__ tokens, const float* __restrict__ emb,
    const float* __restrict__ W1, const float* __restrict__ U1, const float* __restrict__ b1,
    const float* __restrict__ W2, const float* __restrict__ U2, const float* __restrict__ b2,
    const float* __restrict__ Wd, const float* __restrict__ bd, float* __restrict__ out) {
    const int lane = threadIdx.x & 63;
    const int wave = threadIdx.x >> 6;
    const int row0 = blockIdx.x * 16 + wave * 2;
    float bias1[4], bias2[4];
#pragma unroll
    for (int g = 0; g < 4; ++g) { bias1[g] = b1[g * 64 + lane]; bias2[g] = b2[g * 64 + lane]; }
    const float wd = Wd[lane]; const float bdv = bd[0];
    float h1[2] = {0.f, 0.f}, c1[2] = {0.f, 0.f}, h2[2] = {0.f, 0.f}, c2[2] = {0.f, 0.f};
#pragma unroll 1
    for (int t = 0; t < SEQ; ++t) {
        float acc[4][2];
#pragma unroll
        for (int g = 0; g < 4; ++g) { acc[g][0] = bias1[g]; acc[g][1] = bias1[g]; }
        int tokA = __builtin_amdgcn_readfirstlane(tokens[(row0 + 0) * SEQ + t]);
        int tokB = __builtin_amdgcn_readfirstlane(tokens[(row0 + 1) * SEQ + t]);
        const float4* xA = (const float4*)(emb + (size_t)tokA * EMB);
        const float4* xB = (const float4*)(emb + (size_t)tokB * EMB);
#pragma unroll 5
        for (int d4 = 0; d4 < EMB / 4; ++d4) {
            float4 a4 = xA[d4]; float4 b4 = xB[d4];
            float av[4] = {a4.x, a4.y, a4.z, a4.w}; float bv[4] = {b4.x, b4.y, b4.z, b4.w};
#pragma unroll
            for (int e = 0; e < 4; ++e) {
                const float* wrow = W1 + (d4 * 4 + e) * 256;
#pragma unroll
                for (int g = 0; g < 4; ++g) {
                    float wv = wrow[g * 64 + lane];
                    acc[g][0] += av[e] * wv; acc[g][1] += bv[e] * wv;
                }
            }
        }
#pragma unroll 4
        for (int j = 0; j < 64; ++j) {
            float ha = lane_bcast(h1[0], j), hb = lane_bcast(h1[1], j);
            const float* urow = U1 + j * 256;
#pragma unroll
            for (int g = 0; g < 4; ++g) {
                float wv = urow[g * 64 + lane];
                acc[g][0] += ha * wv; acc[g][1] += hb * wv;
            }
        }
#pragma unroll
        for (int r = 0; r < 2; ++r) {
            float ig = sigm_f(acc[0][r]), fg = sigm_f(acc[1][r]);
            float gg = tanh_f(acc[2][r]), og = sigm_f(acc[3][r]);
            c1[r] = fg * c1[r] + ig * gg; h1[r] = og * tanh_f(c1[r]);
        }
        float acc2[4][2];
#pragma unroll
        for (int g = 0; g < 4; ++g) { acc2[g][0] = bias2[g]; acc2[g][1] = bias2[g]; }
#pragma unroll 4
        for (int j = 0; j < 64; ++j) {
            float pa = lane_bcast(h1[0], j), pb = lane_bcast(h1[1], j);
            float qa = lane_bcast(h2[0], j), qb = lane_bcast(h2[1], j);
            const float* w2row = W2 + j * 256; const float* u2row = U2 + j * 256;
#pragma unroll
            for (int g = 0; g < 4; ++g) {
                float w2v = w2row[g * 64 + lane], u2v = u2row[g * 64 + lane];
                acc2[g][0] += pa * w2v + qa * u2v;
                acc2[g][1] += pb * w2v + qb * u2v;
            }
        }
#pragma unroll
        for (int r = 0; r < 2; ++r) {
            float ig = sigm_f(acc2[0][r]), fg = sigm_f(acc2[1][r]);
            float gg = tanh_f(acc2[2][r]), og = sigm_f(acc2[3][r]);
            c2[r] = fg * c2[r] + ig * gg; h2[r] = og * tanh_f(c2[r]);
        }
    }
#pragma unroll
    for (int r = 0; r < 2; ++r) {
        float p = h2[r] * wd;
#pragma unroll
        for (int off = 32; off > 0; off >>= 1) p += __shfl_down(p, off, 64);
        if (lane == 0) out[row0 + r] = sigm_f(p + bdv);
    }
}

extern "C" void kernel_launch(void* const* d_in, const int* in_sizes, int n_in,
                              void* d_out, int out_size, void* d_ws, size_t ws_size,
                              hipStream_t stream) {
    const int*   tokens = (const int*)  d_in[0];
    const float* emb    = (const float*)d_in[1];
    const float* W1     = (const float*)d_in[2];
    const float* U1     = (const float*)d_in[3];
    const float* b1     = (const float*)d_in[4];
    const float* W2     = (const float*)d_in[5];
    const float* U2     = (const float*)d_in[6];
    const float* b2     = (const float*)d_in[7];
    const float* Wd     = (const float*)d_in[8];
    const float* bd     = (const float*)d_in[9];
    float* out = (float*)d_out;

    if (ws_size < (size_t)WS_NEEDED) {
        lstm_fused_fallback<<<256, 512, 0, stream>>>(tokens, emb, W1, U1, b1, W2, U2, b2, Wd, bd, out);
        return;
    }

    char* ws = (char*)d_ws;
    f16*  E1h = (f16*) (ws + WS_E1H_OFF);
    uint* B1f = (uint*)(ws + WS_B1F_OFF);
    uint* B2f = (uint*)(ws + WS_B2F_OFF);

    prep_e1  <<<320, 256, 0, stream>>>(emb, W1, U1, b1, W2, U2, E1h, B1f, B2f);
    lstm_mfma<<<256, 256, 0, stream>>>(tokens, (const uint2*)E1h,
                                       (const uint4*)B1f, (const uint4*)B2f,
                                       b2, Wd, bd, out);
}

// Round 5
// 204.954 us; speedup vs baseline: 1.3775x; 1.3775x over previous
//
#include <hip/hip_runtime.h>

// LstmSequential round 5: barrier-without-vmcnt-drain + deep gather prefetch.
//  prep_e1   : blocks 0..511 compute E1h[v][u][g] fp16 = b1 + emb[v]@W1 (2 indep
//              accumulators to break the dot2 chain); blocks 512..575 pack U1 /
//              [W2;U2] into MFMA B-fragment layout (fp16).
//  lstm_mfma : both LSTM layers + head fused, 256 blocks x 4 waves, 16 rows/block.
//              ONE barrier/step, implemented as raw `s_waitcnt lgkmcnt(0); s_barrier`
//              so global E1 gathers stay IN FLIGHT across barriers (the per-step
//              8B/lane gather from the 5MB table is an HBM miss ~900cyc; round-4's
//              __syncthreads vmcnt(0) drain serialized it every step).
//              E1 gathers issued 2 steps ahead (window ~2 steps >> 900 cyc).
//              Activations: (5,4)-Pade with raw v_rcp_f32 + v_med3 clamp (8 VALU +
//              1 trans; round-4's __fdividef expanded to IEEE div ~12 instrs).
// Fallback to round-1 monolithic kernel if ws too small.

#define VOCAB 10000
#define EMB   100
#define SEQ   80
#define BATCH 4096

typedef _Float16 f16;
typedef _Float16 f16x8 __attribute__((ext_vector_type(8)));
typedef _Float16 half2_t __attribute__((ext_vector_type(2)));
typedef float    f32x4 __attribute__((ext_vector_type(4)));
typedef unsigned int uint;

__device__ __forceinline__ uint pack2(float lo, float hi) {
    return __builtin_bit_cast(uint, __builtin_amdgcn_cvt_pkrtz(lo, hi));
}
__device__ __forceinline__ uint rl_u(uint v, int l) { return (uint)__builtin_amdgcn_readlane((int)v, l); }
__device__ __forceinline__ float dot2(uint a, uint b, float c) {
    return __builtin_amdgcn_fdot2(__builtin_bit_cast(half2_t, a), __builtin_bit_cast(half2_t, b), c, false);
}
__device__ __forceinline__ f32x4 mfma16(uint4 a, uint4 b, f32x4 c) {
    return __builtin_amdgcn_mfma_f32_16x16x32_f16(
        __builtin_bit_cast(f16x8, a), __builtin_bit_cast(f16x8, b), c, 0, 0, 0);
}
// Barrier that drains ONLY LDS ops (lgkmcnt) — global loads stay outstanding.
// Safe: LDS producer->consumer needs lgkmcnt(0)+s_barrier; the E1/token global
// loads have no cross-wave hazard, and the compiler still inserts per-value
// vmcnt waits at their uses.
__device__ __forceinline__ void barrier_lds() {
    asm volatile("s_waitcnt lgkmcnt(0)\n\ts_barrier" ::: "memory");
}

// (5,4)-Pade tanh, clamped. |err| < 7e-4 everywhere, <1e-5 for |x|<=1.5.
// 8 VALU (3 fma-class + mul + rcp + mul + med3) — no IEEE-div expansion.
__device__ __forceinline__ float tanh_p(float x) {
    float x2  = x * x;
    float num = x * __builtin_fmaf(x2, 105.0f + x2, 945.0f);
    float den = __builtin_fmaf(x2, __builtin_fmaf(15.0f, x2, 420.0f), 945.0f);
    float r   = num * __builtin_amdgcn_rcpf(den);
    return __builtin_amdgcn_fmed3f(r, -1.0f, 1.0f);
}
__device__ __forceinline__ float sigm_p(float x) {
    return __builtin_fmaf(0.5f, tanh_p(0.5f * x), 0.5f);
}
__device__ __forceinline__ float sigm_exact(float x) {
    return 1.0f / (1.0f + __expf(-x));
}

// ---------------- workspace layout (bytes) ----------------
#define WS_E1H_OFF 0                 // VOCAB*256 f16  = 5,120,000
#define WS_B1F_OFF 5120000           // 2048 uint4     = 32,768
#define WS_B2F_OFF 5152768           // 4096 uint4     = 65,536
#define WS_NEEDED  5218304

// ---------------- prep_e1: E1 table + B-fragment packing, one kernel ----------------
// B-frag mapping (16x16x32 f16): lane holds B[k = kt*32 + (lane>>4)*8 + j][n = lane&15],
// dword dw holds j=2dw (lo), j=2dw+1 (hi).
__global__ __launch_bounds__(256) void prep_e1(
    const float* __restrict__ emb,
    const float* __restrict__ W1, const float* __restrict__ U1,
    const float* __restrict__ b1,
    const float* __restrict__ W2, const float* __restrict__ U2,
    f16* __restrict__ E1h, uint* __restrict__ B1f, uint* __restrict__ B2f) {
    if (blockIdx.x < 512) {
        // ---- role A: E1h[v*256 + u*4 + g] = b1[g*64+u] + emb[v] @ W1[:, g*64+u] ----
        const int c    = threadIdx.x;
        const int lane = c & 63;
        const int col  = (c & 3) * 64 + (c >> 2);     // gate-minor storage -> coalesced store
        uint w[50];
#pragma unroll
        for (int kp = 0; kp < 50; ++kp)
            w[kp] = pack2(W1[(2 * kp) * 256 + col], W1[(2 * kp + 1) * 256 + col]);
        const float bias = b1[col];
        for (int v = blockIdx.x; v < VOCAB; v += 512) {
            uint ep = 0;
            if (lane < 50) ep = pack2(emb[v * EMB + 2 * lane], emb[v * EMB + 2 * lane + 1]);
            float a0 = bias, a1 = 0.0f;                // 2 chains: halve dep latency
#pragma unroll
            for (int kp = 0; kp < 50; kp += 2) {
                a0 = dot2(w[kp],     rl_u(ep, kp),     a0);
                a1 = dot2(w[kp + 1], rl_u(ep, kp + 1), a1);
            }
            E1h[v * 256 + c] = (f16)(a0 + a1);
        }
    } else {
        // ---- role B: fragment packing ----
        int idx = (blockIdx.x - 512) * 256 + threadIdx.x;   // 0..16383
        if (idx < 8192) {                                   // B1f (U1, 64x256)
            int dw = idx & 3, lane = (idx >> 2) & 63, kt = (idx >> 8) & 1,
                g = (idx >> 9) & 3, w = idx >> 11;
            int k   = kt * 32 + (lane >> 4) * 8 + dw * 2;
            int col = g * 64 + w * 16 + (lane & 15);
            B1f[idx] = pack2(U1[k * 256 + col], U1[(k + 1) * 256 + col]);
        }
        if (idx < 16384) {                                  // B2f ([W2;U2], 128x256)
            int dw = idx & 3, lane = (idx >> 2) & 63, kt = (idx >> 8) & 3,
                g = (idx >> 10) & 3, w = idx >> 12;
            int k   = kt * 32 + (lane >> 4) * 8 + dw * 2;
            int col = g * 64 + w * 16 + (lane & 15);
            float lo = (k < 64) ? W2[k * 256 + col] : U2[(k - 64) * 256 + col];
            float hi = (k < 63) ? W2[(k + 1) * 256 + col] : U2[(k + 1 - 64) * 256 + col];
            B2f[idx] = pack2(lo, hi);
        }
    }
}

// ---------------- fused 2-layer LSTM + head, 1 lgkm-only barrier per step ----------------
// A-buffer (ping-pong buf b): fp16 A-matrix [16 m x 128 k] in fragment layout,
//   f16 index of (m,k) = ((k>>3)*16 + m)*8 + (k&7); lane's kt-frag = uint4 [kt*64+lane].
//   k 0..63 = h1, k 64..127 = h2.
// Step t (parity p = t&1): MFMA1 reads buf[p].h1 | epi1 writes buf[1-p].h1 | BARRIER |
//   gather e1(t+2) | MFMA2 reads buf[1-p].h1 + buf[p].h2 | epi2 writes buf[1-p].h2.
// All LDS RAW/WAR pairs cross >=1 barrier (verified per-region, rounds 4-5).
__global__ __launch_bounds__(256, 1) void lstm_mfma(
    const int* __restrict__ tokens, const uint2* __restrict__ E1h2,
    const uint4* __restrict__ B1f, const uint4* __restrict__ B2f,
    const float* __restrict__ b2, const float* __restrict__ Wd,
    const float* __restrict__ bd, float* __restrict__ out) {
    __shared__ uint4 AbufU[512];                  // 2 bufs x 256 uint4 = 8 KB
    __shared__ float red[64];
    f16* Abuf = (f16*)AbufU;

    const int tid  = threadIdx.x;
    const int w    = tid >> 6;
    const int lane = tid & 63;
    const int q    = lane >> 4;
    const int li   = lane & 15;
    const int u    = w * 16 + li;                 // this lane's unit
    const int row0 = blockIdx.x * 16;

    const uint4 z4 = {0u, 0u, 0u, 0u};
    AbufU[tid] = z4; AbufU[tid + 256] = z4;       // h1[-1] = h2[-1] = 0

    // persistent B fragments
    uint4 b1f[4][2], b2f[4][4];
#pragma unroll
    for (int g = 0; g < 4; ++g) {
#pragma unroll
        for (int kt = 0; kt < 2; ++kt) b1f[g][kt] = B1f[((w * 4 + g) * 2 + kt) * 64 + lane];
#pragma unroll
        for (int kt = 0; kt < 4; ++kt) b2f[g][kt] = B2f[((w * 4 + g) * 4 + kt) * 64 + lane];
    }
    float b2v[4];
#pragma unroll
    for (int g = 0; g < 4; ++g) b2v[g] = b2[g * 64 + u];
    const float wdv = Wd[u];
    const float bdv = bd[0];

    // token window (rows q*4+r) + depth-2 E1 prefetch: e1buf[t&1] holds step t's rows
    int4  tokc[4], tokn[4];
    uint2 e1buf[2][4];
#pragma unroll
    for (int r = 0; r < 4; ++r) {
        tokc[r] = *(const int4*)(tokens + (size_t)(row0 + q * 4 + r) * SEQ);
        e1buf[0][r] = E1h2[(size_t)tokc[r].x * 64 + u];
        e1buf[1][r] = E1h2[(size_t)tokc[r].y * 64 + u];
    }

    float c1[4] = {0.f, 0.f, 0.f, 0.f}, c2[4] = {0.f, 0.f, 0.f, 0.f};
    float h2v[4] = {0.f, 0.f, 0.f, 0.f};

    __syncthreads();                              // init barrier (full drain, once)

#pragma unroll 1
    for (int t4 = 0; t4 < SEQ / 4; ++t4) {
        if (t4 < SEQ / 4 - 1) {
#pragma unroll
            for (int r = 0; r < 4; ++r)
                tokn[r] = *(const int4*)(tokens + (size_t)(row0 + q * 4 + r) * SEQ + (t4 + 1) * 4);
        }
#pragma unroll
        for (int s = 0; s < 4; ++s) {
            const int p = s & 1;                  // == t&1 (flips 4x per t4)
            // ---- layer 1 MFMA: z1 = h1_{t-1} @ U1 ----
            uint4 a0 = AbufU[p * 256 + lane];
            uint4 a1 = AbufU[p * 256 + 64 + lane];
            f32x4 acc[4] = {{0,0,0,0},{0,0,0,0},{0,0,0,0},{0,0,0,0}};
#pragma unroll
            for (int g = 0; g < 4; ++g) acc[g] = mfma16(a0, b1f[g][0], acc[g]);
#pragma unroll
            for (int g = 0; g < 4; ++g) acc[g] = mfma16(a1, b1f[g][1], acc[g]);

            // ---- epilogue 1 (lane-local), consumes e1buf[p], writes h1_t -> buf[1-p] ----
#pragma unroll
            for (int r = 0; r < 4; ++r) {
                half2_t e01 = __builtin_bit_cast(half2_t, e1buf[p][r].x);
                half2_t e23 = __builtin_bit_cast(half2_t, e1buf[p][r].y);
                float ig = sigm_p(acc[0][r] + (float)e01.x);
                float fg = sigm_p(acc[1][r] + (float)e01.y);
                float gv = tanh_p(acc[2][r] + (float)e23.x);
                float og = sigm_p(acc[3][r] + (float)e23.y);
                c1[r] = fg * c1[r] + ig * gv;
                float h1 = og * tanh_p(c1[r]);
                Abuf[(1 - p) * 2048 + ((u >> 3) * 16 + q * 4 + r) * 8 + (u & 7)] = (f16)h1;
            }

            barrier_lds();                        // lgkm-only: gathers stay in flight

            // gather e1 for t+2 into the slot just consumed (in flight ~2 steps)
            if (t4 * 4 + s + 2 < SEQ) {
#pragma unroll
                for (int r = 0; r < 4; ++r) {
                    int tk = (s == 0) ? tokc[r].z : (s == 1) ? tokc[r].w
                           : (s == 2) ? tokn[r].x : tokn[r].y;
                    e1buf[p][r] = E1h2[(size_t)tk * 64 + u];
                }
            }

            // ---- layer 2 MFMA: z2 = [h1_t | h2_{t-1}] @ [W2;U2] ----
            uint4 a[4];
            a[0] = AbufU[(1 - p) * 256 + lane];
            a[1] = AbufU[(1 - p) * 256 + 64 + lane];
            a[2] = AbufU[p * 256 + 128 + lane];
            a[3] = AbufU[p * 256 + 192 + lane];
            f32x4 acc2[4] = {{0,0,0,0},{0,0,0,0},{0,0,0,0},{0,0,0,0}};
#pragma unroll
            for (int kt = 0; kt < 4; ++kt)
#pragma unroll
                for (int g = 0; g < 4; ++g) acc2[g] = mfma16(a[kt], b2f[g][kt], acc2[g]);

            // ---- epilogue 2 (lane-local), writes h2_t -> buf[1-p] ----
#pragma unroll
            for (int r = 0; r < 4; ++r) {
                float ig = sigm_p(acc2[0][r] + b2v[0]);
                float fg = sigm_p(acc2[1][r] + b2v[1]);
                float gv = tanh_p(acc2[2][r] + b2v[2]);
                float og = sigm_p(acc2[3][r] + b2v[3]);
                c2[r] = fg * c2[r] + ig * gv;
                float h2 = og * tanh_p(c2[r]);
                h2v[r] = h2;
                Abuf[(1 - p) * 2048 + 1024 + ((u >> 3) * 16 + q * 4 + r) * 8 + (u & 7)] = (f16)h2;
            }
        }
#pragma unroll
        for (int r = 0; r < 4; ++r) tokc[r] = tokn[r];
    }

    // ---- head: out[row] = sigmoid(sum_u h2[row][u]*Wd[u] + bd) ----
#pragma unroll
    for (int r = 0; r < 4; ++r) {
        float pv = h2v[r] * wdv;
        pv += __shfl_xor(pv, 1, 64);
        pv += __shfl_xor(pv, 2, 64);
        pv += __shfl_xor(pv, 4, 64);
        pv += __shfl_xor(pv, 8, 64);
        if (li == 0) red[w * 16 + q * 4 + r] = pv;
    }
    __syncthreads();
    if (tid < 16) {
        float sum = red[tid] + red[16 + tid] + red[32 + tid] + red[48 + tid] + bdv;
        out[row0 + tid] = sigm_exact(sum);
    }
}

// ---------------- fallback (no workspace): round-1 monolithic ----------------
__device__ __forceinline__ float lane_bcast(float v, int j) {
    return __builtin_bit_cast(float, __builtin_amdgcn_readlane(__builtin_bit_cast(int, v), j));
}
__device__ __forceinline__ float sigm_f(float x)  { return 1.0f / (1.0f + __expf(-x)); }
__device__ __forceinline__ float tanh_f(float x)  { return 2.0f / (1.0f + __expf(-2.0f * x)) - 1.0f; }

__global__ __launch_bounds__(512) void lstm_fused_fallback(
    const int* __restrict__ tokens, const float* __restrict__ emb,
    const float* __restrict__ W1, const float* __restrict__ U1, const float* __restrict__ b1,
    const float* __restrict__ W2, const float* __restrict__ U2, const float* __restrict__ b2,
    const float* __restrict__ Wd, const float* __restrict__ bd, float* __restrict__ out) {
    const int lane = threadIdx.x & 63;
    const int wave = threadIdx.x >> 6;
    const int row0 = blockIdx.x * 16 + wave * 2;
    float bias1[4], bias2[4];
#pragma unroll
    for (int g = 0; g < 4; ++g) { bias1[g] = b1[g * 64 + lane]; bias2[g] = b2[g * 64 + lane]; }
    const float wd = Wd[lane]; const float bdv = bd[0];
    float h1[2] = {0.f, 0.f}, c1[2] = {0.f, 0.f}, h2[2] = {0.f, 0.f}, c2[2] = {0.f, 0.f};
#pragma unroll 1
    for (int t = 0; t < SEQ; ++t) {
        float acc[4][2];
#pragma unroll
        for (int g = 0; g < 4; ++g) { acc[g][0] = bias1[g]; acc[g][1] = bias1[g]; }
        int tokA = __builtin_amdgcn_readfirstlane(tokens[(row0 + 0) * SEQ + t]);
        int tokB = __builtin_amdgcn_readfirstlane(tokens[(row0 + 1) * SEQ + t]);
        const float4* xA = (const float4*)(emb + (size_t)tokA * EMB);
        const float4* xB = (const float4*)(emb + (size_t)tokB * EMB);
#pragma unroll 5
        for (int d4 = 0; d4 < EMB / 4; ++d4) {
            float4 a4 = xA[d4]; float4 b4 = xB[d4];
            float av[4] = {a4.x, a4.y, a4.z, a4.w}; float bv[4] = {b4.x, b4.y, b4.z, b4.w};
#pragma unroll
            for (int e = 0; e < 4; ++e) {
                const float* wrow = W1 + (d4 * 4 + e) * 256;
#pragma unroll
                for (int g = 0; g < 4; ++g) {
                    float wv = wrow[g * 64 + lane];
                    acc[g][0] += av[e] * wv; acc[g][1] += bv[e] * wv;
                }
            }
        }
#pragma unroll 4
        for (int j = 0; j < 64; ++j) {
            float ha = lane_bcast(h1[0], j), hb = lane_bcast(h1[1], j);
            const float* urow = U1 + j * 256;
#pragma unroll
            for (int g = 0; g < 4; ++g) {
                float wv = urow[g * 64 + lane];
                acc[g][0] += ha * wv; acc[g][1] += hb * wv;
            }
        }
#pragma unroll
        for (int r = 0; r < 2; ++r) {
            float ig = sigm_f(acc[0][r]), fg = sigm_f(acc[1][r]);
            float gg = tanh_f(acc[2][r]), og = sigm_f(acc[3][r]);
            c1[r] = fg * c1[r] + ig * gg; h1[r] = og * tanh_f(c1[r]);
        }
        float acc2[4][2];
#pragma unroll
        for (int g = 0; g < 4; ++g) { acc2[g][0] = bias2[g]; acc2[g][1] = bias2[g]; }
#pragma unroll 4
        for (int j = 0; j < 64; ++j) {
            float pa = lane_bcast(h1[0], j), pb = lane_bcast(h1[1], j);
            float qa = lane_bcast(h2[0], j), qb = lane_bcast(h2[1], j);
            const float* w2row = W2 + j * 256; const float* u2row = U2 + j * 256;
#pragma unroll
            for (int g = 0; g < 4; ++g) {
                float w2v = w2row[g * 64 + lane], u2v = u2row[g * 64 + lane];
                acc2[g][0] += pa * w2v + qa * u2v;
                acc2[g][1] += pb * w2v + qb * u2v;
            }
        }
#pragma unroll
        for (int r = 0; r < 2; ++r) {
            float ig = sigm_f(acc2[0][r]), fg = sigm_f(acc2[1][r]);
            float gg = tanh_f(acc2[2][r]), og = sigm_f(acc2[3][r]);
            c2[r] = fg * c2[r] + ig * gg; h2[r] = og * tanh_f(c2[r]);
        }
    }
#pragma unroll
    for (int r = 0; r < 2; ++r) {
        float p = h2[r] * wd;
#pragma unroll
        for (int off = 32; off > 0; off >>= 1) p += __shfl_down(p, off, 64);
        if (lane == 0) out[row0 + r] = sigm_f(p + bdv);
    }
}

extern "C" void kernel_launch(void* const* d_in, const int* in_sizes, int n_in,
                              void* d_out, int out_size, void* d_ws, size_t ws_size,
                              hipStream_t stream) {
    const int*   tokens = (const int*)  d_in[0];
    const float* emb    = (const float*)d_in[1];
    const float* W1     = (const float*)d_in[2];
    const float* U1     = (const float*)d_in[3];
    const float* b1     = (const float*)d_in[4];
    const float* W2     = (const float*)d_in[5];
    const float* U2     = (const float*)d_in[6];
    const float* b2     = (const float*)d_in[7];
    const float* Wd     = (const float*)d_in[8];
    const float* bd     = (const float*)d_in[9];
    float* out = (float*)d_out;

    if (ws_size < (size_t)WS_NEEDED) {
        lstm_fused_fallback<<<256, 512, 0, stream>>>(tokens, emb, W1, U1, b1, W2, U2, b2, Wd, bd, out);
        return;
    }

    char* ws = (char*)d_ws;
    f16*  E1h = (f16*) (ws + WS_E1H_OFF);
    uint* B1f = (uint*)(ws + WS_B1F_OFF);
    uint* B2f = (uint*)(ws + WS_B2F_OFF);

    prep_e1  <<<576, 256, 0, stream>>>(emb, W1, U1, b1, W2, U2, E1h, B1f, B2f);
    lstm_mfma<<<256, 256, 0, stream>>>(tokens, (const uint2*)E1h,
                                       (const uint4*)B1f, (const uint4*)B2f,
                                       b2, Wd, bd, out);
}

// Round 6
// 195.406 us; speedup vs baseline: 1.4449x; 1.0489x over previous
//
#include <hip/hip_runtime.h>

// LstmSequential round 6: 2 blocks/CU TLP (512 blocks x 8 rows), quad-aligned row map.
//  prep_e1   : blocks 0..1023 compute E1h[v][u][g] fp16 = b1 + emb[v]@W1 (prefetched
//              emb, 2 dot2 chains); blocks 1024..1087 pack U1 / [W2;U2] into MFMA
//              B-fragment layout (fp16).
//  lstm_mfma : both LSTM layers + head fused. 512 blocks x 4 waves, 8 rows/block.
//              KEY: batch rows sit at tile-rows {4q, 4q+1} (D-row = 4*quad + reg), so
//              every quad owns exactly 2 rows -> per-wave epilogue VALU halves and the
//              2nd co-resident block (launch_bounds(256,2)) fills the issue bubbles
//              round 5 exposed (VALUBusy 65% @ 1 wave/SIMD).
//              1 lgkm-only barrier/step (s_waitcnt lgkmcnt(0); s_barrier) keeps E1
//              gathers in flight across steps; depth-2 gather prefetch.
// Fallback to round-1 monolithic kernel if ws too small.

#define VOCAB 10000
#define EMB   100
#define SEQ   80
#define BATCH 4096

typedef _Float16 f16;
typedef _Float16 f16x8 __attribute__((ext_vector_type(8)));
typedef _Float16 half2_t __attribute__((ext_vector_type(2)));
typedef float    f32x4 __attribute__((ext_vector_type(4)));
typedef unsigned int uint;

__device__ __forceinline__ uint pack2(float lo, float hi) {
    return __builtin_bit_cast(uint, __builtin_amdgcn_cvt_pkrtz(lo, hi));
}
__device__ __forceinline__ uint rl_u(uint v, int l) { return (uint)__builtin_amdgcn_readlane((int)v, l); }
__device__ __forceinline__ float dot2(uint a, uint b, float c) {
    return __builtin_amdgcn_fdot2(__builtin_bit_cast(half2_t, a), __builtin_bit_cast(half2_t, b), c, false);
}
__device__ __forceinline__ f32x4 mfma16(uint4 a, uint4 b, f32x4 c) {
    return __builtin_amdgcn_mfma_f32_16x16x32_f16(
        __builtin_bit_cast(f16x8, a), __builtin_bit_cast(f16x8, b), c, 0, 0, 0);
}
// Barrier draining ONLY LDS ops — global gathers stay outstanding (compiler still
// inserts per-value vmcnt waits at their uses; no cross-wave hazard on globals).
__device__ __forceinline__ void barrier_lds() {
    asm volatile("s_waitcnt lgkmcnt(0)\n\ts_barrier" ::: "memory");
}

// (5,4)-Pade tanh, clamped. |err| < 7e-4 everywhere, <1e-5 for |x|<=1.5.
__device__ __forceinline__ float tanh_p(float x) {
    float x2  = x * x;
    float num = x * __builtin_fmaf(x2, 105.0f + x2, 945.0f);
    float den = __builtin_fmaf(x2, __builtin_fmaf(15.0f, x2, 420.0f), 945.0f);
    float r   = num * __builtin_amdgcn_rcpf(den);
    return __builtin_amdgcn_fmed3f(r, -1.0f, 1.0f);
}
__device__ __forceinline__ float sigm_p(float x) {
    return __builtin_fmaf(0.5f, tanh_p(0.5f * x), 0.5f);
}
__device__ __forceinline__ float sigm_exact(float x) {
    return 1.0f / (1.0f + __expf(-x));
}

// ---------------- workspace layout (bytes) ----------------
#define WS_E1H_OFF 0                 // VOCAB*256 f16  = 5,120,000
#define WS_B1F_OFF 5120000           // 2048 uint4     = 32,768
#define WS_B2F_OFF 5152768           // 4096 uint4     = 65,536
#define WS_NEEDED  5218304

// ---------------- prep_e1: E1 table + B-fragment packing ----------------
// B-frag mapping (16x16x32 f16): lane holds B[k = kt*32 + (lane>>4)*8 + j][n = lane&15],
// dword dw holds j=2dw (lo), j=2dw+1 (hi).
#define NBA 1024
__global__ __launch_bounds__(256) void prep_e1(
    const float* __restrict__ emb,
    const float* __restrict__ W1, const float* __restrict__ U1,
    const float* __restrict__ b1,
    const float* __restrict__ W2, const float* __restrict__ U2,
    f16* __restrict__ E1h, uint* __restrict__ B1f, uint* __restrict__ B2f) {
    if (blockIdx.x < NBA) {
        // ---- role A: E1h[v*256 + u*4 + g] = b1[g*64+u] + emb[v] @ W1[:, g*64+u] ----
        const int c    = threadIdx.x;
        const int lane = c & 63;
        const int col  = (c & 3) * 64 + (c >> 2);     // gate-minor storage -> coalesced store
        uint w[50];
#pragma unroll
        for (int kp = 0; kp < 50; ++kp)
            w[kp] = pack2(W1[(2 * kp) * 256 + col], W1[(2 * kp + 1) * 256 + col]);
        const float bias = b1[col];
        float2 ecur = {0.f, 0.f};
        if (lane < 50) ecur = *(const float2*)(emb + (size_t)blockIdx.x * EMB + 2 * lane);
        for (int v = blockIdx.x; v < VOCAB; v += NBA) {
            float2 enext = {0.f, 0.f};
            if (v + NBA < VOCAB && lane < 50)
                enext = *(const float2*)(emb + (size_t)(v + NBA) * EMB + 2 * lane);
            uint ep = pack2(ecur.x, ecur.y);
            float a0 = bias, a1 = 0.0f;                // 2 chains
#pragma unroll
            for (int kp = 0; kp < 50; kp += 2) {
                a0 = dot2(w[kp],     rl_u(ep, kp),     a0);
                a1 = dot2(w[kp + 1], rl_u(ep, kp + 1), a1);
            }
            E1h[v * 256 + c] = (f16)(a0 + a1);
            ecur = enext;
        }
    } else {
        // ---- role B: fragment packing ----
        int idx = (blockIdx.x - NBA) * 256 + threadIdx.x;   // 0..16383
        if (idx < 8192) {                                   // B1f (U1, 64x256)
            int dw = idx & 3, lane = (idx >> 2) & 63, kt = (idx >> 8) & 1,
                g = (idx >> 9) & 3, w = idx >> 11;
            int k   = kt * 32 + (lane >> 4) * 8 + dw * 2;
            int col = g * 64 + w * 16 + (lane & 15);
            B1f[idx] = pack2(U1[k * 256 + col], U1[(k + 1) * 256 + col]);
        }
        if (idx < 16384) {                                  // B2f ([W2;U2], 128x256)
            int dw = idx & 3, lane = (idx >> 2) & 63, kt = (idx >> 8) & 3,
                g = (idx >> 10) & 3, w = idx >> 12;
            int k   = kt * 32 + (lane >> 4) * 8 + dw * 2;
            int col = g * 64 + w * 16 + (lane & 15);
            float lo = (k < 64) ? W2[k * 256 + col] : U2[(k - 64) * 256 + col];
            float hi = (k < 63) ? W2[(k + 1) * 256 + col] : U2[(k + 1 - 64) * 256 + col];
            B2f[idx] = pack2(lo, hi);
        }
    }
}

// ---------------- fused 2-layer LSTM + head, 8 rows/block, 2 blocks/CU ----------------
// A-buffer (ping-pong buf b): fp16 A-matrix [16 m x 128 k] in fragment layout,
//   f16 index of (m,k) = ((k>>3)*16 + m)*8 + (k&7); lane's kt-frag = uint4 [kt*64+lane].
//   k 0..63 = h1, k 64..127 = h2.
// Row map: batch row (row0 + q*2 + r) lives at tile-row m = 4q + r (r=0,1); tile-rows
// 4q+2, 4q+3 are zero forever. D-row = 4*quad + reg -> each quad's regs 0,1 are its
// 2 batch rows; regs 2,3 unused.
// Step t (parity p = t&1): MFMA1 reads buf[p].h1 | epi1 writes buf[1-p].h1 | BARRIER |
//   gather e1(t+2) | MFMA2 reads buf[1-p].h1 + buf[p].h2 | epi2 writes buf[1-p].h2.
__global__ __launch_bounds__(256, 2) void lstm_mfma(
    const int* __restrict__ tokens, const uint2* __restrict__ E1h2,
    const uint4* __restrict__ B1f, const uint4* __restrict__ B2f,
    const float* __restrict__ b2, const float* __restrict__ Wd,
    const float* __restrict__ bd, float* __restrict__ out) {
    __shared__ uint4 AbufU[512];                  // 2 bufs x 256 uint4 = 8 KB
    __shared__ float red[32];
    f16* Abuf = (f16*)AbufU;

    const int tid  = threadIdx.x;
    const int w    = tid >> 6;
    const int lane = tid & 63;
    const int q    = lane >> 4;
    const int li   = lane & 15;
    const int u    = w * 16 + li;                 // this lane's unit (output col)
    const int row0 = blockIdx.x * 8;

    const uint4 z4 = {0u, 0u, 0u, 0u};
    AbufU[tid] = z4; AbufU[tid + 256] = z4;       // h1[-1] = h2[-1] = 0 (and pad rows)

    // persistent B fragments
    uint4 b1f[4][2], b2f[4][4];
#pragma unroll
    for (int g = 0; g < 4; ++g) {
#pragma unroll
        for (int kt = 0; kt < 2; ++kt) b1f[g][kt] = B1f[((w * 4 + g) * 2 + kt) * 64 + lane];
#pragma unroll
        for (int kt = 0; kt < 4; ++kt) b2f[g][kt] = B2f[((w * 4 + g) * 4 + kt) * 64 + lane];
    }
    float b2v[4];
#pragma unroll
    for (int g = 0; g < 4; ++g) b2v[g] = b2[g * 64 + u];
    const float wdv = Wd[u];
    const float bdv = bd[0];

    // token window (rows q*2+r) + depth-2 E1 prefetch: e1buf[t&1] holds step t's rows
    int4  tokc[2], tokn[2];
    uint2 e1buf[2][2];
#pragma unroll
    for (int r = 0; r < 2; ++r) {
        tokc[r] = *(const int4*)(tokens + (size_t)(row0 + q * 2 + r) * SEQ);
        e1buf[0][r] = E1h2[(size_t)tokc[r].x * 64 + u];
        e1buf[1][r] = E1h2[(size_t)tokc[r].y * 64 + u];
    }

    float c1[2] = {0.f, 0.f}, c2[2] = {0.f, 0.f};
    float h2v[2] = {0.f, 0.f};

    __syncthreads();                              // init barrier (full drain, once)

#pragma unroll 1
    for (int t4 = 0; t4 < SEQ / 4; ++t4) {
        if (t4 < SEQ / 4 - 1) {
#pragma unroll
            for (int r = 0; r < 2; ++r)
                tokn[r] = *(const int4*)(tokens + (size_t)(row0 + q * 2 + r) * SEQ + (t4 + 1) * 4);
        }
#pragma unroll
        for (int s = 0; s < 4; ++s) {
            const int p = s & 1;                  // == t&1
            // ---- layer 1 MFMA: z1 = h1_{t-1} @ U1 ----
            uint4 a0 = AbufU[p * 256 + lane];
            uint4 a1 = AbufU[p * 256 + 64 + lane];
            f32x4 acc[4] = {{0,0,0,0},{0,0,0,0},{0,0,0,0},{0,0,0,0}};
#pragma unroll
            for (int g = 0; g < 4; ++g) acc[g] = mfma16(a0, b1f[g][0], acc[g]);
#pragma unroll
            for (int g = 0; g < 4; ++g) acc[g] = mfma16(a1, b1f[g][1], acc[g]);

            // ---- epilogue 1 (lane-local, 2 rows), writes h1_t -> buf[1-p] ----
#pragma unroll
            for (int r = 0; r < 2; ++r) {
                half2_t e01 = __builtin_bit_cast(half2_t, e1buf[p][r].x);
                half2_t e23 = __builtin_bit_cast(half2_t, e1buf[p][r].y);
                float ig = sigm_p(acc[0][r] + (float)e01.x);
                float fg = sigm_p(acc[1][r] + (float)e01.y);
                float gv = tanh_p(acc[2][r] + (float)e23.x);
                float og = sigm_p(acc[3][r] + (float)e23.y);
                c1[r] = fg * c1[r] + ig * gv;
                float h1 = og * tanh_p(c1[r]);
                Abuf[(1 - p) * 2048 + ((u >> 3) * 16 + 4 * q + r) * 8 + (u & 7)] = (f16)h1;
            }

            barrier_lds();                        // lgkm-only: gathers stay in flight

            // gather e1 for t+2 into the slot just consumed
            if (t4 * 4 + s + 2 < SEQ) {
#pragma unroll
                for (int r = 0; r < 2; ++r) {
                    int tk = (s == 0) ? tokc[r].z : (s == 1) ? tokc[r].w
                           : (s == 2) ? tokn[r].x : tokn[r].y;
                    e1buf[p][r] = E1h2[(size_t)tk * 64 + u];
                }
            }

            // ---- layer 2 MFMA: z2 = [h1_t | h2_{t-1}] @ [W2;U2] + b2 ----
            uint4 a[4];
            a[0] = AbufU[(1 - p) * 256 + lane];
            a[1] = AbufU[(1 - p) * 256 + 64 + lane];
            a[2] = AbufU[p * 256 + 128 + lane];
            a[3] = AbufU[p * 256 + 192 + lane];
            f32x4 acc2[4];
#pragma unroll
            for (int g = 0; g < 4; ++g)
                acc2[g] = (f32x4){b2v[g], b2v[g], b2v[g], b2v[g]};
#pragma unroll
            for (int kt = 0; kt < 4; ++kt)
#pragma unroll
                for (int g = 0; g < 4; ++g) acc2[g] = mfma16(a[kt], b2f[g][kt], acc2[g]);

            // ---- epilogue 2 (lane-local, 2 rows), writes h2_t -> buf[1-p] ----
#pragma unroll
            for (int r = 0; r < 2; ++r) {
                float ig = sigm_p(acc2[0][r]);
                float fg = sigm_p(acc2[1][r]);
                float gv = tanh_p(acc2[2][r]);
                float og = sigm_p(acc2[3][r]);
                c2[r] = fg * c2[r] + ig * gv;
                float h2 = og * tanh_p(c2[r]);
                h2v[r] = h2;
                Abuf[(1 - p) * 2048 + 1024 + ((u >> 3) * 16 + 4 * q + r) * 8 + (u & 7)] = (f16)h2;
            }
        }
#pragma unroll
        for (int r = 0; r < 2; ++r) tokc[r] = tokn[r];
    }

    // ---- head: out[row] = sigmoid(sum_u h2[row][u]*Wd[u] + bd) ----
#pragma unroll
    for (int r = 0; r < 2; ++r) {
        float pv = h2v[r] * wdv;
        pv += __shfl_xor(pv, 1, 64);
        pv += __shfl_xor(pv, 2, 64);
        pv += __shfl_xor(pv, 4, 64);
        pv += __shfl_xor(pv, 8, 64);
        if (li == 0) red[w * 8 + q * 2 + r] = pv;   // per-wave partial for local row
    }
    __syncthreads();
    if (tid < 8) {
        float sum = red[tid] + red[8 + tid] + red[16 + tid] + red[24 + tid] + bdv;
        out[row0 + tid] = sigm_exact(sum);
    }
}

// ---------------- fallback (no workspace): round-1 monolithic ----------------
__device__ __forceinline__ float lane_bcast(float v, int j) {
    return __builtin_bit_cast(float, __builtin_amdgcn_readlane(__builtin_bit_cast(int, v), j));
}
__device__ __forceinline__ float sigm_f(float x)  { return 1.0f / (1.0f + __expf(-x)); }
__device__ __forceinline__ float tanh_f(float x)  { return 2.0f / (1.0f + __expf(-2.0f * x)) - 1.0f; }

__global__ __launch_bounds__(512) void lstm_fused_fallback(
    const int* __restrict__ tokens, const float* __restrict__ emb,
    const float* __restrict__ W1, const float* __restrict__ U1, const float* __restrict__ b1,
    const float* __restrict__ W2, const float* __restrict__ U2, const float* __restrict__ b2,
    const float* __restrict__ Wd, const float* __restrict__ bd, float* __restrict__ out) {
    const int lane = threadIdx.x & 63;
    const int wave = threadIdx.x >> 6;
    const int row0 = blockIdx.x * 16 + wave * 2;
    float bias1[4], bias2[4];
#pragma unroll
    for (int g = 0; g < 4; ++g) { bias1[g] = b1[g * 64 + lane]; bias2[g] = b2[g * 64 + lane]; }
    const float wd = Wd[lane]; const float bdv = bd[0];
    float h1[2] = {0.f, 0.f}, c1[2] = {0.f, 0.f}, h2[2] = {0.f, 0.f}, c2[2] = {0.f, 0.f};
#pragma unroll 1
    for (int t = 0; t < SEQ; ++t) {
        float acc[4][2];
#pragma unroll
        for (int g = 0; g < 4; ++g) { acc[g][0] = bias1[g]; acc[g][1] = bias1[g]; }
        int tokA = __builtin_amdgcn_readfirstlane(tokens[(row0 + 0) * SEQ + t]);
        int tokB = __builtin_amdgcn_readfirstlane(tokens[(row0 + 1) * SEQ + t]);
        const float4* xA = (const float4*)(emb + (size_t)tokA * EMB);
        const float4* xB = (const float4*)(emb + (size_t)tokB * EMB);
#pragma unroll 5
        for (int d4 = 0; d4 < EMB / 4; ++d4) {
            float4 a4 = xA[d4]; float4 b4 = xB[d4];
            float av[4] = {a4.x, a4.y, a4.z, a4.w}; float bv[4] = {b4.x, b4.y, b4.z, b4.w};
#pragma unroll
            for (int e = 0; e < 4; ++e) {
                const float* wrow = W1 + (d4 * 4 + e) * 256;
#pragma unroll
                for (int g = 0; g < 4; ++g) {
                    float wv = wrow[g * 64 + lane];
                    acc[g][0] += av[e] * wv; acc[g][1] += bv[e] * wv;
                }
            }
        }
#pragma unroll 4
        for (int j = 0; j < 64; ++j) {
            float ha = lane_bcast(h1[0], j), hb = lane_bcast(h1[1], j);
            const float* urow = U1 + j * 256;
#pragma unroll
            for (int g = 0; g < 4; ++g) {
                float wv = urow[g * 64 + lane];
                acc[g][0] += ha * wv; acc[g][1] += hb * wv;
            }
        }
#pragma unroll
        for (int r = 0; r < 2; ++r) {
            float ig = sigm_f(acc[0][r]), fg = sigm_f(acc[1][r]);
            float gg = tanh_f(acc[2][r]), og = sigm_f(acc[3][r]);
            c1[r] = fg * c1[r] + ig * gg; h1[r] = og * tanh_f(c1[r]);
        }
        float acc2[4][2];
#pragma unroll
        for (int g = 0; g < 4; ++g) { acc2[g][0] = bias2[g]; acc2[g][1] = bias2[g]; }
#pragma unroll 4
        for (int j = 0; j < 64; ++j) {
            float pa = lane_bcast(h1[0], j), pb = lane_bcast(h1[1], j);
            float qa = lane_bcast(h2[0], j), qb = lane_bcast(h2[1], j);
            const float* w2row = W2 + j * 256; const float* u2row = U2 + j * 256;
#pragma unroll
            for (int g = 0; g < 4; ++g) {
                float w2v = w2row[g * 64 + lane], u2v = u2row[g * 64 + lane];
                acc2[g][0] += pa * w2v + qa * u2v;
                acc2[g][1] += pb * w2v + qb * u2v;
            }
        }
#pragma unroll
        for (int r = 0; r < 2; ++r) {
            float ig = sigm_f(acc2[0][r]), fg = sigm_f(acc2[1][r]);
            float gg = tanh_f(acc2[2][r]), og = sigm_f(acc2[3][r]);
            c2[r] = fg * c2[r] + ig * gg; h2[r] = og * tanh_f(c2[r]);
        }
    }
#pragma unroll
    for (int r = 0; r < 2; ++r) {
        float p = h2[r] * wd;
#pragma unroll
        for (int off = 32; off > 0; off >>= 1) p += __shfl_down(p, off, 64);
        if (lane == 0) out[row0 + r] = sigm_f(p + bdv);
    }
}

extern "C" void kernel_launch(void* const* d_in, const int* in_sizes, int n_in,
                              void* d_out, int out_size, void* d_ws, size_t ws_size,
                              hipStream_t stream) {
    const int*   tokens = (const int*)  d_in[0];
    const float* emb    = (const float*)d_in[1];
    const float* W1     = (const float*)d_in[2];
    const float* U1     = (const float*)d_in[3];
    const float* b1     = (const float*)d_in[4];
    const float* W2     = (const float*)d_in[5];
    const float* U2     = (const float*)d_in[6];
    const float* b2     = (const float*)d_in[7];
    const float* Wd     = (const float*)d_in[8];
    const float* bd     = (const float*)d_in[9];
    float* out = (float*)d_out;

    if (ws_size < (size_t)WS_NEEDED) {
        lstm_fused_fallback<<<256, 512, 0, stream>>>(tokens, emb, W1, U1, b1, W2, U2, b2, Wd, bd, out);
        return;
    }

    char* ws = (char*)d_ws;
    f16*  E1h = (f16*) (ws + WS_E1H_OFF);
    uint* B1f = (uint*)(ws + WS_B1F_OFF);
    uint* B2f = (uint*)(ws + WS_B2F_OFF);

    prep_e1  <<<NBA + 64, 256, 0, stream>>>(emb, W1, U1, b1, W2, U2, E1h, B1f, B2f);
    lstm_mfma<<<512, 256, 0, stream>>>(tokens, (const uint2*)E1h,
                                       (const uint4*)B1f, (const uint4*)B2f,
                                       b2, Wd, bd, out);
}

// Round 7
// 174.714 us; speedup vs baseline: 1.6160x; 1.1184x over previous
//
#include <hip/hip_runtime.h>

// LstmSequential round 7: issue-count reduction at the fixed 2-blocks/CU shape.
//  - exp2-based sigmoid/tanh (4-5 ops, graceful inf saturation) replace Pade (9-11).
//  - E1 table is f32 [v][u][4g] (float4 gather) folded straight into MFMA acc init
//    (regs 0,1 = live rows; regs 2,3 zero) -> no cvt/add in epilogue 1.
//  - prep_e1 role-A uses identity thread->col mapping so all W1 loads coalesce;
//    the layout permutation moved to the (cheap, L2-buffered) E1 store.
//  Shape unchanged from r6: 512 blocks x 4 waves, 8 rows/block, rows at tile-rows
//  {4q,4q+1}, 1 lgkm-only barrier/step, depth-2 E1 gather prefetch.
// Fallback to round-1 monolithic kernel if ws too small.

#define VOCAB 10000
#define EMB   100
#define SEQ   80
#define BATCH 4096

typedef _Float16 f16;
typedef _Float16 f16x8 __attribute__((ext_vector_type(8)));
typedef _Float16 half2_t __attribute__((ext_vector_type(2)));
typedef float    f32x4 __attribute__((ext_vector_type(4)));
typedef unsigned int uint;

#define LOG2E 1.4426950408889634f

__device__ __forceinline__ uint pack2(float lo, float hi) {
    return __builtin_bit_cast(uint, __builtin_amdgcn_cvt_pkrtz(lo, hi));
}
__device__ __forceinline__ uint rl_u(uint v, int l) { return (uint)__builtin_amdgcn_readlane((int)v, l); }
__device__ __forceinline__ float dot2(uint a, uint b, float c) {
    return __builtin_amdgcn_fdot2(__builtin_bit_cast(half2_t, a), __builtin_bit_cast(half2_t, b), c, false);
}
__device__ __forceinline__ f32x4 mfma16(uint4 a, uint4 b, f32x4 c) {
    return __builtin_amdgcn_mfma_f32_16x16x32_f16(
        __builtin_bit_cast(f16x8, a), __builtin_bit_cast(f16x8, b), c, 0, 0, 0);
}
// Barrier draining ONLY LDS ops — global gathers stay outstanding.
__device__ __forceinline__ void barrier_lds() {
    asm volatile("s_waitcnt lgkmcnt(0)\n\ts_barrier" ::: "memory");
}

// exp2-based activations: v_mul + v_exp + v_add + v_rcp (+ v_fma for tanh).
// Saturate gracefully: exp2->inf -> rcp->0 -> sigm->0 / tanh->+-1. Rel err ~1e-6.
__device__ __forceinline__ float sigm_e(float x) {
    float t = __builtin_amdgcn_exp2f(-LOG2E * x);
    return __builtin_amdgcn_rcpf(1.0f + t);
}
__device__ __forceinline__ float tanh_e(float x) {
    float t = __builtin_amdgcn_exp2f((2.0f * LOG2E) * x);
    return __builtin_fmaf(-2.0f, __builtin_amdgcn_rcpf(1.0f + t), 1.0f);
}
__device__ __forceinline__ float sigm_exact(float x) {
    return 1.0f / (1.0f + __expf(-x));
}

// ---------------- workspace layout (bytes) ----------------
#define WS_E1F_OFF 0                 // VOCAB*256 f32  = 10,240,000
#define WS_B1F_OFF 10240000          // 2048 uint4     = 32,768
#define WS_B2F_OFF 10272768          // 4096 uint4     = 65,536
#define WS_NEEDED  10338304

// ---------------- prep_e1: E1 table + B-fragment packing ----------------
// B-frag mapping (16x16x32 f16): lane holds B[k = kt*32 + (lane>>4)*8 + j][n = lane&15],
// dword dw holds j=2dw (lo), j=2dw+1 (hi).
#define NB_E1 512
__global__ __launch_bounds__(256) void prep_e1(
    const float* __restrict__ emb,
    const float* __restrict__ W1, const float* __restrict__ U1,
    const float* __restrict__ b1,
    const float* __restrict__ W2, const float* __restrict__ U2,
    float* __restrict__ E1f, uint* __restrict__ B1f, uint* __restrict__ B2f) {
    if (blockIdx.x < NB_E1) {
        // ---- role A: thread c owns raw col c (g = c>>6, u = c&63).
        // W1 loads coalesce (stride-1 across threads); permutation applied at store:
        // E1f[v*256 + u*4 + g].
        const int c    = threadIdx.x;
        const int lane = c & 63;
        uint w[50];
#pragma unroll
        for (int kp = 0; kp < 50; ++kp)
            w[kp] = pack2(W1[(2 * kp) * 256 + c], W1[(2 * kp + 1) * 256 + c]);
        const float bias = b1[c];
        const int   dst  = (c & 63) * 4 + (c >> 6);
        float2 ecur = {0.f, 0.f};
        if (lane < 50) ecur = *(const float2*)(emb + (size_t)blockIdx.x * EMB + 2 * lane);
        for (int v = blockIdx.x; v < VOCAB; v += NB_E1) {
            float2 enext = {0.f, 0.f};
            if (v + NB_E1 < VOCAB && lane < 50)
                enext = *(const float2*)(emb + (size_t)(v + NB_E1) * EMB + 2 * lane);
            uint ep = pack2(ecur.x, ecur.y);
            float a0 = bias, a1 = 0.0f;                // 2 chains
#pragma unroll
            for (int kp = 0; kp < 50; kp += 2) {
                a0 = dot2(w[kp],     rl_u(ep, kp),     a0);
                a1 = dot2(w[kp + 1], rl_u(ep, kp + 1), a1);
            }
            E1f[v * 256 + dst] = a0 + a1;
            ecur = enext;
        }
    } else {
        // ---- role B: fragment packing ----
        int idx = (blockIdx.x - NB_E1) * 256 + threadIdx.x;   // 0..16383
        if (idx < 8192) {                                     // B1f (U1, 64x256)
            int dw = idx & 3, lane = (idx >> 2) & 63, kt = (idx >> 8) & 1,
                g = (idx >> 9) & 3, w = idx >> 11;
            int k   = kt * 32 + (lane >> 4) * 8 + dw * 2;
            int col = g * 64 + w * 16 + (lane & 15);
            B1f[idx] = pack2(U1[k * 256 + col], U1[(k + 1) * 256 + col]);
        }
        if (idx < 16384) {                                    // B2f ([W2;U2], 128x256)
            int dw = idx & 3, lane = (idx >> 2) & 63, kt = (idx >> 8) & 3,
                g = (idx >> 10) & 3, w = idx >> 12;
            int k   = kt * 32 + (lane >> 4) * 8 + dw * 2;
            int col = g * 64 + w * 16 + (lane & 15);
            float lo = (k < 64) ? W2[k * 256 + col] : U2[(k - 64) * 256 + col];
            float hi = (k < 63) ? W2[(k + 1) * 256 + col] : U2[(k + 1 - 64) * 256 + col];
            B2f[idx] = pack2(lo, hi);
        }
    }
}

// ---------------- fused 2-layer LSTM + head, 8 rows/block, 2 blocks/CU ----------------
// A-buffer (ping-pong buf b): fp16 A-matrix [16 m x 128 k] in fragment layout,
//   f16 index of (m,k) = ((k>>3)*16 + m)*8 + (k&7); lane's kt-frag = uint4 [kt*64+lane].
//   k 0..63 = h1, k 64..127 = h2.
// Row map: batch row (row0 + q*2 + r) at tile-row m = 4q + r (r=0,1); tile-rows
// 4q+2, 4q+3 are zero forever (acc regs 2,3 garbage, never read).
// Step t (parity p = t&1): MFMA1 reads buf[p].h1 | epi1 writes buf[1-p].h1 | BARRIER |
//   gather e1(t+2) | MFMA2 reads buf[1-p].h1 + buf[p].h2 | epi2 writes buf[1-p].h2.
__global__ __launch_bounds__(256, 2) void lstm_mfma(
    const int* __restrict__ tokens, const f32x4* __restrict__ E1f4,
    const uint4* __restrict__ B1f, const uint4* __restrict__ B2f,
    const float* __restrict__ b2, const float* __restrict__ Wd,
    const float* __restrict__ bd, float* __restrict__ out) {
    __shared__ uint4 AbufU[512];                  // 2 bufs x 256 uint4 = 8 KB
    __shared__ float red[32];
    f16* Abuf = (f16*)AbufU;

    const int tid  = threadIdx.x;
    const int w    = tid >> 6;
    const int lane = tid & 63;
    const int q    = lane >> 4;
    const int li   = lane & 15;
    const int u    = w * 16 + li;                 // this lane's unit (output col)
    const int row0 = blockIdx.x * 8;

    const uint4 z4 = {0u, 0u, 0u, 0u};
    AbufU[tid] = z4; AbufU[tid + 256] = z4;       // h1[-1] = h2[-1] = 0 (and pad rows)

    // persistent B fragments
    uint4 b1f[4][2], b2f[4][4];
#pragma unroll
    for (int g = 0; g < 4; ++g) {
#pragma unroll
        for (int kt = 0; kt < 2; ++kt) b1f[g][kt] = B1f[((w * 4 + g) * 2 + kt) * 64 + lane];
#pragma unroll
        for (int kt = 0; kt < 4; ++kt) b2f[g][kt] = B2f[((w * 4 + g) * 4 + kt) * 64 + lane];
    }
    float b2v[4];
#pragma unroll
    for (int g = 0; g < 4; ++g) b2v[g] = b2[g * 64 + u];
    const float wdv = Wd[u];
    const float bdv = bd[0];

    // token window (rows q*2+r) + depth-2 E1 prefetch: e1buf[t&1] holds step t's rows
    int4  tokc[2], tokn[2];
    f32x4 e1buf[2][2];
#pragma unroll
    for (int r = 0; r < 2; ++r) {
        tokc[r] = *(const int4*)(tokens + (size_t)(row0 + q * 2 + r) * SEQ);
        e1buf[0][r] = E1f4[(size_t)tokc[r].x * 64 + u];
        e1buf[1][r] = E1f4[(size_t)tokc[r].y * 64 + u];
    }

    float c1[2] = {0.f, 0.f}, c2[2] = {0.f, 0.f};
    float h2v[2] = {0.f, 0.f};

    __syncthreads();                              // init barrier (full drain, once)

#pragma unroll 1
    for (int t4 = 0; t4 < SEQ / 4; ++t4) {
        if (t4 < SEQ / 4 - 1) {
#pragma unroll
            for (int r = 0; r < 2; ++r)
                tokn[r] = *(const int4*)(tokens + (size_t)(row0 + q * 2 + r) * SEQ + (t4 + 1) * 4);
        }
#pragma unroll
        for (int s = 0; s < 4; ++s) {
            const int p = s & 1;                  // == t&1
            // ---- layer 1 MFMA: z1 = e1 (in C) + h1_{t-1} @ U1 ----
            uint4 a0 = AbufU[p * 256 + lane];
            uint4 a1 = AbufU[p * 256 + 64 + lane];
            f32x4 acc[4];
#pragma unroll
            for (int g = 0; g < 4; ++g)
                acc[g] = (f32x4){e1buf[p][0][g], e1buf[p][1][g], 0.f, 0.f};
#pragma unroll
            for (int g = 0; g < 4; ++g) acc[g] = mfma16(a0, b1f[g][0], acc[g]);
#pragma unroll
            for (int g = 0; g < 4; ++g) acc[g] = mfma16(a1, b1f[g][1], acc[g]);

            // ---- epilogue 1 (lane-local, 2 rows), writes h1_t -> buf[1-p] ----
#pragma unroll
            for (int r = 0; r < 2; ++r) {
                float ig = sigm_e(acc[0][r]);
                float fg = sigm_e(acc[1][r]);
                float gv = tanh_e(acc[2][r]);
                float og = sigm_e(acc[3][r]);
                c1[r] = fg * c1[r] + ig * gv;
                float h1 = og * tanh_e(c1[r]);
                Abuf[(1 - p) * 2048 + ((u >> 3) * 16 + 4 * q + r) * 8 + (u & 7)] = (f16)h1;
            }

            barrier_lds();                        // lgkm-only: gathers stay in flight

            // gather e1 for t+2 into the slot just consumed
            if (t4 * 4 + s + 2 < SEQ) {
#pragma unroll
                for (int r = 0; r < 2; ++r) {
                    int tk = (s == 0) ? tokc[r].z : (s == 1) ? tokc[r].w
                           : (s == 2) ? tokn[r].x : tokn[r].y;
                    e1buf[p][r] = E1f4[(size_t)tk * 64 + u];
                }
            }

            // ---- layer 2 MFMA: z2 = b2 (in C) + [h1_t | h2_{t-1}] @ [W2;U2] ----
            uint4 a[4];
            a[0] = AbufU[(1 - p) * 256 + lane];
            a[1] = AbufU[(1 - p) * 256 + 64 + lane];
            a[2] = AbufU[p * 256 + 128 + lane];
            a[3] = AbufU[p * 256 + 192 + lane];
            f32x4 acc2[4];
#pragma unroll
            for (int g = 0; g < 4; ++g)
                acc2[g] = (f32x4){b2v[g], b2v[g], 0.f, 0.f};
#pragma unroll
            for (int kt = 0; kt < 4; ++kt)
#pragma unroll
                for (int g = 0; g < 4; ++g) acc2[g] = mfma16(a[kt], b2f[g][kt], acc2[g]);

            // ---- epilogue 2 (lane-local, 2 rows), writes h2_t -> buf[1-p] ----
#pragma unroll
            for (int r = 0; r < 2; ++r) {
                float ig = sigm_e(acc2[0][r]);
                float fg = sigm_e(acc2[1][r]);
                float gv = tanh_e(acc2[2][r]);
                float og = sigm_e(acc2[3][r]);
                c2[r] = fg * c2[r] + ig * gv;
                float h2 = og * tanh_e(c2[r]);
                h2v[r] = h2;
                Abuf[(1 - p) * 2048 + 1024 + ((u >> 3) * 16 + 4 * q + r) * 8 + (u & 7)] = (f16)h2;
            }
        }
#pragma unroll
        for (int r = 0; r < 2; ++r) tokc[r] = tokn[r];
    }

    // ---- head: out[row] = sigmoid(sum_u h2[row][u]*Wd[u] + bd) ----
#pragma unroll
    for (int r = 0; r < 2; ++r) {
        float pv = h2v[r] * wdv;
        pv += __shfl_xor(pv, 1, 64);
        pv += __shfl_xor(pv, 2, 64);
        pv += __shfl_xor(pv, 4, 64);
        pv += __shfl_xor(pv, 8, 64);
        if (li == 0) red[w * 8 + q * 2 + r] = pv;   // per-wave partial for local row
    }
    __syncthreads();
    if (tid < 8) {
        float sum = red[tid] + red[8 + tid] + red[16 + tid] + red[24 + tid] + bdv;
        out[row0 + tid] = sigm_exact(sum);
    }
}

// ---------------- fallback (no workspace): round-1 monolithic ----------------
__device__ __forceinline__ float lane_bcast(float v, int j) {
    return __builtin_bit_cast(float, __builtin_amdgcn_readlane(__builtin_bit_cast(int, v), j));
}
__device__ __forceinline__ float sigm_f(float x)  { return 1.0f / (1.0f + __expf(-x)); }
__device__ __forceinline__ float tanh_f(float x)  { return 2.0f / (1.0f + __expf(-2.0f * x)) - 1.0f; }

__global__ __launch_bounds__(512) void lstm_fused_fallback(
    const int* __restrict__ tokens, const float* __restrict__ emb,
    const float* __restrict__ W1, const float* __restrict__ U1, const float* __restrict__ b1,
    const float* __restrict__ W2, const float* __restrict__ U2, const float* __restrict__ b2,
    const float* __restrict__ Wd, const float* __restrict__ bd, float* __restrict__ out) {
    const int lane = threadIdx.x & 63;
    const int wave = threadIdx.x >> 6;
    const int row0 = blockIdx.x * 16 + wave * 2;
    float bias1[4], bias2[4];
#pragma unroll
    for (int g = 0; g < 4; ++g) { bias1[g] = b1[g * 64 + lane]; bias2[g] = b2[g * 64 + lane]; }
    const float wd = Wd[lane]; const float bdv = bd[0];
    float h1[2] = {0.f, 0.f}, c1[2] = {0.f, 0.f}, h2[2] = {0.f, 0.f}, c2[2] = {0.f, 0.f};
#pragma unroll 1
    for (int t = 0; t < SEQ; ++t) {
        float acc[4][2];
#pragma unroll
        for (int g = 0; g < 4; ++g) { acc[g][0] = bias1[g]; acc[g][1] = bias1[g]; }
        int tokA = __builtin_amdgcn_readfirstlane(tokens[(row0 + 0) * SEQ + t]);
        int tokB = __builtin_amdgcn_readfirstlane(tokens[(row0 + 1) * SEQ + t]);
        const float4* xA = (const float4*)(emb + (size_t)tokA * EMB);
        const float4* xB = (const float4*)(emb + (size_t)tokB * EMB);
#pragma unroll 5
        for (int d4 = 0; d4 < EMB / 4; ++d4) {
            float4 a4 = xA[d4]; float4 b4 = xB[d4];
            float av[4] = {a4.x, a4.y, a4.z, a4.w}; float bv[4] = {b4.x, b4.y, b4.z, b4.w};
#pragma unroll
            for (int e = 0; e < 4; ++e) {
                const float* wrow = W1 + (d4 * 4 + e) * 256;
#pragma unroll
                for (int g = 0; g < 4; ++g) {
                    float wv = wrow[g * 64 + lane];
                    acc[g][0] += av[e] * wv; acc[g][1] += bv[e] * wv;
                }
            }
        }
#pragma unroll 4
        for (int j = 0; j < 64; ++j) {
            float ha = lane_bcast(h1[0], j), hb = lane_bcast(h1[1], j);
            const float* urow = U1 + j * 256;
#pragma unroll
            for (int g = 0; g < 4; ++g) {
                float wv = urow[g * 64 + lane];
                acc[g][0] += ha * wv; acc[g][1] += hb * wv;
            }
        }
#pragma unroll
        for (int r = 0; r < 2; ++r) {
            float ig = sigm_f(acc[0][r]), fg = sigm_f(acc[1][r]);
            float gg = tanh_f(acc[2][r]), og = sigm_f(acc[3][r]);
            c1[r] = fg * c1[r] + ig * gg; h1[r] = og * tanh_f(c1[r]);
        }
        float acc2[4][2];
#pragma unroll
        for (int g = 0; g < 4; ++g) { acc2[g][0] = bias2[g]; acc2[g][1] = bias2[g]; }
#pragma unroll 4
        for (int j = 0; j < 64; ++j) {
            float pa = lane_bcast(h1[0], j), pb = lane_bcast(h1[1], j);
            float qa = lane_bcast(h2[0], j), qb = lane_bcast(h2[1], j);
            const float* w2row = W2 + j * 256; const float* u2row = U2 + j * 256;
#pragma unroll
            for (int g = 0; g < 4; ++g) {
                float w2v = w2row[g * 64 + lane], u2v = u2row[g * 64 + lane];
                acc2[g][0] += pa * w2v + qa * u2v;
                acc2[g][1] += pb * w2v + qb * u2v;
            }
        }
#pragma unroll
        for (int r = 0; r < 2; ++r) {
            float ig = sigm_f(acc2[0][r]), fg = sigm_f(acc2[1][r]);
            float gg = tanh_f(acc2[2][r]), og = sigm_f(acc2[3][r]);
            c2[r] = fg * c2[r] + ig * gg; h2[r] = og * tanh_f(c2[r]);
        }
    }
#pragma unroll
    for (int r = 0; r < 2; ++r) {
        float p = h2[r] * wd;
#pragma unroll
        for (int off = 32; off > 0; off >>= 1) p += __shfl_down(p, off, 64);
        if (lane == 0) out[row0 + r] = sigm_f(p + bdv);
    }
}

extern "C" void kernel_launch(void* const* d_in, const int* in_sizes, int n_in,
                              void* d_out, int out_size, void* d_ws, size_t ws_size,
                              hipStream_t stream) {
    const int*   tokens = (const int*)  d_in[0];
    const float* emb    = (const float*)d_in[1];
    const float* W1     = (const float*)d_in[2];
    const float* U1     = (const float*)d_in[3];
    const float* b1     = (const float*)d_in[4];
    const float* W2     = (const float*)d_in[5];
    const float* U2     = (const float*)d_in[6];
    const float* b2     = (const float*)d_in[7];
    const float* Wd     = (const float*)d_in[8];
    const float* bd     = (const float*)d_in[9];
    float* out = (float*)d_out;

    if (ws_size < (size_t)WS_NEEDED) {
        lstm_fused_fallback<<<256, 512, 0, stream>>>(tokens, emb, W1, U1, b1, W2, U2, b2, Wd, bd, out);
        return;
    }

    char* ws = (char*)d_ws;
    float* E1f = (float*)(ws + WS_E1F_OFF);
    uint*  B1f = (uint*) (ws + WS_B1F_OFF);
    uint*  B2f = (uint*) (ws + WS_B2F_OFF);

    prep_e1  <<<NB_E1 + 64, 256, 0, stream>>>(emb, W1, U1, b1, W2, U2, E1f, B1f, B2f);
    lstm_mfma<<<512, 256, 0, stream>>>(tokens, (const f32x4*)E1f,
                                       (const uint4*)B1f, (const uint4*)B2f,
                                       b2, Wd, bd, out);
}

// Round 8
// 174.353 us; speedup vs baseline: 1.6193x; 1.0021x over previous
//
#include <hip/hip_runtime.h>

// LstmSequential round 8: register-cached h1 fragments + dead-reg elision.
//  - MFMA2(t)'s h1 ds_reads are reused as MFMA1(t+1)'s A-operand (same LDS region,
//    re-read was redundant): -2 ds_read_b128/wave/step and MFMA1 leaves the LDS
//    critical path entirely (opens each step with pure register MFMA).
//  - acc regs 2,3 (garbage rows, never read) left undefined: -16 v_mov/wave/step.
//  - t+2 E1 gather issued BEFORE the barrier (token regs only -> no LDS hazard).
//  Shape unchanged: 512 blocks x 4 waves, 8 rows/block at tile-rows {4q,4q+1},
//  2 blocks/CU, 1 lgkm-only barrier/step, f32 E1 folded into acc init.
// Fallback to round-1 monolithic kernel if ws too small.

#define VOCAB 10000
#define EMB   100
#define SEQ   80
#define BATCH 4096

typedef _Float16 f16;
typedef _Float16 f16x8 __attribute__((ext_vector_type(8)));
typedef _Float16 half2_t __attribute__((ext_vector_type(2)));
typedef float    f32x4 __attribute__((ext_vector_type(4)));
typedef unsigned int uint;

#define LOG2E 1.4426950408889634f

__device__ __forceinline__ uint pack2(float lo, float hi) {
    return __builtin_bit_cast(uint, __builtin_amdgcn_cvt_pkrtz(lo, hi));
}
__device__ __forceinline__ uint rl_u(uint v, int l) { return (uint)__builtin_amdgcn_readlane((int)v, l); }
__device__ __forceinline__ float dot2(uint a, uint b, float c) {
    return __builtin_amdgcn_fdot2(__builtin_bit_cast(half2_t, a), __builtin_bit_cast(half2_t, b), c, false);
}
__device__ __forceinline__ f32x4 mfma16(uint4 a, uint4 b, f32x4 c) {
    return __builtin_amdgcn_mfma_f32_16x16x32_f16(
        __builtin_bit_cast(f16x8, a), __builtin_bit_cast(f16x8, b), c, 0, 0, 0);
}
// Barrier draining ONLY LDS ops — global gathers stay outstanding.
__device__ __forceinline__ void barrier_lds() {
    asm volatile("s_waitcnt lgkmcnt(0)\n\ts_barrier" ::: "memory");
}

// exp2-based activations (issue-minimal: 2 trans + 2-3 VALU; saturate gracefully).
__device__ __forceinline__ float sigm_e(float x) {
    float t = __builtin_amdgcn_exp2f(-LOG2E * x);
    return __builtin_amdgcn_rcpf(1.0f + t);
}
__device__ __forceinline__ float tanh_e(float x) {
    float t = __builtin_amdgcn_exp2f((2.0f * LOG2E) * x);
    return __builtin_fmaf(-2.0f, __builtin_amdgcn_rcpf(1.0f + t), 1.0f);
}
__device__ __forceinline__ float sigm_exact(float x) {
    return 1.0f / (1.0f + __expf(-x));
}

// ---------------- workspace layout (bytes) ----------------
#define WS_E1F_OFF 0                 // VOCAB*256 f32  = 10,240,000
#define WS_B1F_OFF 10240000          // 2048 uint4     = 32,768
#define WS_B2F_OFF 10272768          // 4096 uint4     = 65,536
#define WS_NEEDED  10338304

// ---------------- prep_e1: E1 table + B-fragment packing ----------------
#define NB_E1 512
__global__ __launch_bounds__(256) void prep_e1(
    const float* __restrict__ emb,
    const float* __restrict__ W1, const float* __restrict__ U1,
    const float* __restrict__ b1,
    const float* __restrict__ W2, const float* __restrict__ U2,
    float* __restrict__ E1f, uint* __restrict__ B1f, uint* __restrict__ B2f) {
    if (blockIdx.x < NB_E1) {
        // role A: thread c owns raw col c; W1 loads coalesce; store applies the
        // [v][u][g] permutation: E1f[v*256 + u*4 + g].
        const int c    = threadIdx.x;
        const int lane = c & 63;
        uint w[50];
#pragma unroll
        for (int kp = 0; kp < 50; ++kp)
            w[kp] = pack2(W1[(2 * kp) * 256 + c], W1[(2 * kp + 1) * 256 + c]);
        const float bias = b1[c];
        const int   dst  = (c & 63) * 4 + (c >> 6);
        float2 ecur = {0.f, 0.f};
        if (lane < 50) ecur = *(const float2*)(emb + (size_t)blockIdx.x * EMB + 2 * lane);
        for (int v = blockIdx.x; v < VOCAB; v += NB_E1) {
            float2 enext = {0.f, 0.f};
            if (v + NB_E1 < VOCAB && lane < 50)
                enext = *(const float2*)(emb + (size_t)(v + NB_E1) * EMB + 2 * lane);
            uint ep = pack2(ecur.x, ecur.y);
            float a0 = bias, a1 = 0.0f;
#pragma unroll
            for (int kp = 0; kp < 50; kp += 2) {
                a0 = dot2(w[kp],     rl_u(ep, kp),     a0);
                a1 = dot2(w[kp + 1], rl_u(ep, kp + 1), a1);
            }
            E1f[v * 256 + dst] = a0 + a1;
            ecur = enext;
        }
    } else {
        // role B: B-fragment packing (16x16x32 f16 layout:
        // lane holds B[k = kt*32 + (lane>>4)*8 + j][n = lane&15], dw: j=2dw,2dw+1)
        int idx = (blockIdx.x - NB_E1) * 256 + threadIdx.x;   // 0..16383
        if (idx < 8192) {                                     // B1f (U1, 64x256)
            int dw = idx & 3, lane = (idx >> 2) & 63, kt = (idx >> 8) & 1,
                g = (idx >> 9) & 3, w = idx >> 11;
            int k   = kt * 32 + (lane >> 4) * 8 + dw * 2;
            int col = g * 64 + w * 16 + (lane & 15);
            B1f[idx] = pack2(U1[k * 256 + col], U1[(k + 1) * 256 + col]);
        }
        if (idx < 16384) {                                    // B2f ([W2;U2], 128x256)
            int dw = idx & 3, lane = (idx >> 2) & 63, kt = (idx >> 8) & 3,
                g = (idx >> 10) & 3, w = idx >> 12;
            int k   = kt * 32 + (lane >> 4) * 8 + dw * 2;
            int col = g * 64 + w * 16 + (lane & 15);
            float lo = (k < 64) ? W2[k * 256 + col] : U2[(k - 64) * 256 + col];
            float hi = (k < 63) ? W2[(k + 1) * 256 + col] : U2[(k + 1 - 64) * 256 + col];
            B2f[idx] = pack2(lo, hi);
        }
    }
}

// ---------------- fused 2-layer LSTM + head ----------------
// A-buffer (ping-pong buf b): fp16 A-matrix [16 m x 128 k] in fragment layout,
//   f16 index of (m,k) = ((k>>3)*16 + m)*8 + (k&7); lane's kt-frag = uint4 [kt*64+lane].
//   k 0..63 = h1, k 64..127 = h2. Rows at tile-rows {4q, 4q+1}; {4q+2,4q+3} dead.
// Step t (p = t&1):
//   MFMA1 uses REGISTER-CACHED h1(t-1) frags (a0c,a1c; seeded 0) -> no LDS read.
//   epi1 writes buf[1-p].h1 | gather e1(t+2) | BARRIER |
//   MFMA2 ds_reads buf[1-p].h1 (->also next step's cache) + buf[p].h2 | epi2 writes
//   buf[1-p].h2.
// Hazards: h1 region read post-barrier(t), rewritten pre-barrier(t+2) -> crosses
// barrier(t+1) ok; h2 write(t, post-B(t)) read by MFMA2(t+1) post-B(t+1) ok.
__global__ __launch_bounds__(256, 2) void lstm_mfma(
    const int* __restrict__ tokens, const f32x4* __restrict__ E1f4,
    const uint4* __restrict__ B1f, const uint4* __restrict__ B2f,
    const float* __restrict__ b2, const float* __restrict__ Wd,
    const float* __restrict__ bd, float* __restrict__ out) {
    __shared__ uint4 AbufU[512];                  // 2 bufs x 256 uint4 = 8 KB
    __shared__ float red[32];
    f16* Abuf = (f16*)AbufU;

    const int tid  = threadIdx.x;
    const int w    = tid >> 6;
    const int lane = tid & 63;
    const int q    = lane >> 4;
    const int li   = lane & 15;
    const int u    = w * 16 + li;                 // this lane's unit (output col)
    const int row0 = blockIdx.x * 8;

    const uint4 z4 = {0u, 0u, 0u, 0u};
    AbufU[tid] = z4; AbufU[tid + 256] = z4;       // zero both buffers (h2(-1)=0 read)

    // persistent B fragments
    uint4 b1f[4][2], b2f[4][4];
#pragma unroll
    for (int g = 0; g < 4; ++g) {
#pragma unroll
        for (int kt = 0; kt < 2; ++kt) b1f[g][kt] = B1f[((w * 4 + g) * 2 + kt) * 64 + lane];
#pragma unroll
        for (int kt = 0; kt < 4; ++kt) b2f[g][kt] = B2f[((w * 4 + g) * 4 + kt) * 64 + lane];
    }
    float b2v[4];
#pragma unroll
    for (int g = 0; g < 4; ++g) b2v[g] = b2[g * 64 + u];
    const float wdv = Wd[u];
    const float bdv = bd[0];

    // token window + depth-2 E1 prefetch
    int4  tokc[2], tokn[2];
    f32x4 e1buf[2][2];
#pragma unroll
    for (int r = 0; r < 2; ++r) {
        tokc[r] = *(const int4*)(tokens + (size_t)(row0 + q * 2 + r) * SEQ);
        e1buf[0][r] = E1f4[(size_t)tokc[r].x * 64 + u];
        e1buf[1][r] = E1f4[(size_t)tokc[r].y * 64 + u];
    }

    float c1[2] = {0.f, 0.f}, c2[2] = {0.f, 0.f};
    float h2v[2] = {0.f, 0.f};
    uint4 a0c = z4, a1c = z4;                     // cached h1(t-1) A-frags; h1(-1)=0

    __syncthreads();                              // init barrier (full drain, once)

#pragma unroll 1
    for (int t4 = 0; t4 < SEQ / 4; ++t4) {
        if (t4 < SEQ / 4 - 1) {
#pragma unroll
            for (int r = 0; r < 2; ++r)
                tokn[r] = *(const int4*)(tokens + (size_t)(row0 + q * 2 + r) * SEQ + (t4 + 1) * 4);
        }
#pragma unroll
        for (int s = 0; s < 4; ++s) {
            const int p = s & 1;                  // == t&1
            // ---- layer 1 MFMA: z1 = e1 (in C) + h1_{t-1} @ U1 — pure registers ----
            f32x4 acc[4];
#pragma unroll
            for (int g = 0; g < 4; ++g) {         // regs 2,3 left undefined (dead rows)
                acc[g][0] = e1buf[p][0][g];
                acc[g][1] = e1buf[p][1][g];
            }
#pragma unroll
            for (int g = 0; g < 4; ++g) acc[g] = mfma16(a0c, b1f[g][0], acc[g]);
#pragma unroll
            for (int g = 0; g < 4; ++g) acc[g] = mfma16(a1c, b1f[g][1], acc[g]);

            // ---- epilogue 1 (2 rows), writes h1_t -> buf[1-p] ----
#pragma unroll
            for (int r = 0; r < 2; ++r) {
                float ig = sigm_e(acc[0][r]);
                float fg = sigm_e(acc[1][r]);
                float gv = tanh_e(acc[2][r]);
                float og = sigm_e(acc[3][r]);
                c1[r] = fg * c1[r] + ig * gv;
                float h1 = og * tanh_e(c1[r]);
                Abuf[(1 - p) * 2048 + ((u >> 3) * 16 + 4 * q + r) * 8 + (u & 7)] = (f16)h1;
            }

            // gather e1 for t+2 (registers only — safe pre-barrier, max in-flight)
            if (t4 * 4 + s + 2 < SEQ) {
#pragma unroll
                for (int r = 0; r < 2; ++r) {
                    int tk = (s == 0) ? tokc[r].z : (s == 1) ? tokc[r].w
                           : (s == 2) ? tokn[r].x : tokn[r].y;
                    e1buf[p][r] = E1f4[(size_t)tk * 64 + u];
                }
            }

            barrier_lds();                        // lgkm-only: gathers stay in flight

            // ---- layer 2 MFMA: z2 = b2 (in C) + [h1_t | h2_{t-1}] @ [W2;U2] ----
            uint4 a[4];
            a[0] = AbufU[(1 - p) * 256 + lane];   // h1(t) — cached for next MFMA1
            a[1] = AbufU[(1 - p) * 256 + 64 + lane];
            a[2] = AbufU[p * 256 + 128 + lane];   // h2(t-1)
            a[3] = AbufU[p * 256 + 192 + lane];
            f32x4 acc2[4];
#pragma unroll
            for (int g = 0; g < 4; ++g) {         // regs 2,3 left undefined
                acc2[g][0] = b2v[g];
                acc2[g][1] = b2v[g];
            }
#pragma unroll
            for (int kt = 0; kt < 4; ++kt)
#pragma unroll
                for (int g = 0; g < 4; ++g) acc2[g] = mfma16(a[kt], b2f[g][kt], acc2[g]);
            a0c = a[0]; a1c = a[1];               // h1(t) becomes MFMA1(t+1)'s A

            // ---- epilogue 2 (2 rows), writes h2_t -> buf[1-p] ----
#pragma unroll
            for (int r = 0; r < 2; ++r) {
                float ig = sigm_e(acc2[0][r]);
                float fg = sigm_e(acc2[1][r]);
                float gv = tanh_e(acc2[2][r]);
                float og = sigm_e(acc2[3][r]);
                c2[r] = fg * c2[r] + ig * gv;
                float h2 = og * tanh_e(c2[r]);
                h2v[r] = h2;
                Abuf[(1 - p) * 2048 + 1024 + ((u >> 3) * 16 + 4 * q + r) * 8 + (u & 7)] = (f16)h2;
            }
        }
#pragma unroll
        for (int r = 0; r < 2; ++r) tokc[r] = tokn[r];
    }

    // ---- head: out[row] = sigmoid(sum_u h2[row][u]*Wd[u] + bd) ----
#pragma unroll
    for (int r = 0; r < 2; ++r) {
        float pv = h2v[r] * wdv;
        pv += __shfl_xor(pv, 1, 64);
        pv += __shfl_xor(pv, 2, 64);
        pv += __shfl_xor(pv, 4, 64);
        pv += __shfl_xor(pv, 8, 64);
        if (li == 0) red[w * 8 + q * 2 + r] = pv;
    }
    __syncthreads();
    if (tid < 8) {
        float sum = red[tid] + red[8 + tid] + red[16 + tid] + red[24 + tid] + bdv;
        out[row0 + tid] = sigm_exact(sum);
    }
}

// ---------------- fallback (no workspace): round-1 monolithic ----------------
__device__ __forceinline__ float lane_bcast(float v, int j) {
    return __builtin_bit_cast(float, __builtin_amdgcn_readlane(__builtin_bit_cast(int, v), j));
}
__device__ __forceinline__ float sigm_f(float x)  { return 1.0f / (1.0f + __expf(-x)); }
__device__ __forceinline__ float tanh_f(float x)  { return 2.0f / (1.0f + __expf(-2.0f * x)) - 1.0f; }

__global__ __launch_bounds__(512) void lstm_fused_fallback(
    const int* __restrict__ tokens, const float* __restrict__ emb,
    const float* __restrict__ W1, const float* __restrict__ U1, const float* __restrict__ b1,
    const float* __restrict__ W2, const float* __restrict__ U2, const float* __restrict__ b2,
    const float* __restrict__ Wd, const float* __restrict__ bd, float* __restrict__ out) {
    const int lane = threadIdx.x & 63;
    const int wave = threadIdx.x >> 6;
    const int row0 = blockIdx.x * 16 + wave * 2;
    float bias1[4], bias2[4];
#pragma unroll
    for (int g = 0; g < 4; ++g) { bias1[g] = b1[g * 64 + lane]; bias2[g] = b2[g * 64 + lane]; }
    const float wd = Wd[lane]; const float bdv = bd[0];
    float h1[2] = {0.f, 0.f}, c1[2] = {0.f, 0.f}, h2[2] = {0.f, 0.f}, c2[2] = {0.f, 0.f};
#pragma unroll 1
    for (int t = 0; t < SEQ; ++t) {
        float acc[4][2];
#pragma unroll
        for (int g = 0; g < 4; ++g) { acc[g][0] = bias1[g]; acc[g][1] = bias1[g]; }
        int tokA = __builtin_amdgcn_readfirstlane(tokens[(row0 + 0) * SEQ + t]);
        int tokB = __builtin_amdgcn_readfirstlane(tokens[(row0 + 1) * SEQ + t]);
        const float4* xA = (const float4*)(emb + (size_t)tokA * EMB);
        const float4* xB = (const float4*)(emb + (size_t)tokB * EMB);
#pragma unroll 5
        for (int d4 = 0; d4 < EMB / 4; ++d4) {
            float4 a4 = xA[d4]; float4 b4 = xB[d4];
            float av[4] = {a4.x, a4.y, a4.z, a4.w}; float bv[4] = {b4.x, b4.y, b4.z, b4.w};
#pragma unroll
            for (int e = 0; e < 4; ++e) {
                const float* wrow = W1 + (d4 * 4 + e) * 256;
#pragma unroll
                for (int g = 0; g < 4; ++g) {
                    float wv = wrow[g * 64 + lane];
                    acc[g][0] += av[e] * wv; acc[g][1] += bv[e] * wv;
                }
            }
        }
#pragma unroll 4
        for (int j = 0; j < 64; ++j) {
            float ha = lane_bcast(h1[0], j), hb = lane_bcast(h1[1], j);
            const float* urow = U1 + j * 256;
#pragma unroll
            for (int g = 0; g < 4; ++g) {
                float wv = urow[g * 64 + lane];
                acc[g][0] += ha * wv; acc[g][1] += hb * wv;
            }
        }
#pragma unroll
        for (int r = 0; r < 2; ++r) {
            float ig = sigm_f(acc[0][r]), fg = sigm_f(acc[1][r]);
            float gg = tanh_f(acc[2][r]), og = sigm_f(acc[3][r]);
            c1[r] = fg * c1[r] + ig * gg; h1[r] = og * tanh_f(c1[r]);
        }
        float acc2[4][2];
#pragma unroll
        for (int g = 0; g < 4; ++g) { acc2[g][0] = bias2[g]; acc2[g][1] = bias2[g]; }
#pragma unroll 4
        for (int j = 0; j < 64; ++j) {
            float pa = lane_bcast(h1[0], j), pb = lane_bcast(h1[1], j);
            float qa = lane_bcast(h2[0], j), qb = lane_bcast(h2[1], j);
            const float* w2row = W2 + j * 256; const float* u2row = U2 + j * 256;
#pragma unroll
            for (int g = 0; g < 4; ++g) {
                float w2v = w2row[g * 64 + lane], u2v = u2row[g * 64 + lane];
                acc2[g][0] += pa * w2v + qa * u2v;
                acc2[g][1] += pb * w2v + qb * u2v;
            }
        }
#pragma unroll
        for (int r = 0; r < 2; ++r) {
            float ig = sigm_f(acc2[0][r]), fg = sigm_f(acc2[1][r]);
            float gg = tanh_f(acc2[2][r]), og = sigm_f(acc2[3][r]);
            c2[r] = fg * c2[r] + ig * gg; h2[r] = og * tanh_f(c2[r]);
        }
    }
#pragma unroll
    for (int r = 0; r < 2; ++r) {
        float p = h2[r] * wd;
#pragma unroll
        for (int off = 32; off > 0; off >>= 1) p += __shfl_down(p, off, 64);
        if (lane == 0) out[row0 + r] = sigm_f(p + bdv);
    }
}

extern "C" void kernel_launch(void* const* d_in, const int* in_sizes, int n_in,
                              void* d_out, int out_size, void* d_ws, size_t ws_size,
                              hipStream_t stream) {
    const int*   tokens = (const int*)  d_in[0];
    const float* emb    = (const float*)d_in[1];
    const float* W1     = (const float*)d_in[2];
    const float* U1     = (const float*)d_in[3];
    const float* b1     = (const float*)d_in[4];
    const float* W2     = (const float*)d_in[5];
    const float* U2     = (const float*)d_in[6];
    const float* b2     = (const float*)d_in[7];
    const float* Wd     = (const float*)d_in[8];
    const float* bd     = (const float*)d_in[9];
    float* out = (float*)d_out;

    if (ws_size < (size_t)WS_NEEDED) {
        lstm_fused_fallback<<<256, 512, 0, stream>>>(tokens, emb, W1, U1, b1, W2, U2, b2, Wd, bd, out);
        return;
    }

    char* ws = (char*)d_ws;
    float* E1f = (float*)(ws + WS_E1F_OFF);
    uint*  B1f = (uint*) (ws + WS_B1F_OFF);
    uint*  B2f = (uint*) (ws + WS_B2F_OFF);

    prep_e1  <<<NB_E1 + 64, 256, 0, stream>>>(emb, W1, U1, b1, W2, U2, E1f, B1f, B2f);
    lstm_mfma<<<512, 256, 0, stream>>>(tokens, (const f32x4*)E1f,
                                       (const uint4*)B1f, (const uint4*)B2f,
                                       b2, Wd, bd, out);
}